// Round 11
// baseline (796.025 us; speedup 1.0000x reference)
//
#include <hip/hip_runtime.h>
#include <hip/hip_bf16.h>

#define NODES_H 128
#define HBITS 7   // 128 = 1<<7

typedef __attribute__((ext_vector_type(8))) short bf16x8;
typedef __attribute__((ext_vector_type(4))) float f32x4;

static __device__ __forceinline__ short f2bf(float f) {
    union { float f; unsigned u; } v; v.f = f;
    unsigned r = v.u + 0x7FFFu + ((v.u >> 16) & 1u);  // RNE
    return (short)(r >> 16);
}
static __device__ __forceinline__ float bf2f(unsigned short u) {
    union { unsigned u; float f; } v; v.u = ((unsigned)u) << 16;
    return v.f;
}
// fast sigmoid/tanh via native v_exp_f32 (2^x) + v_rcp_f32 (~1 ulp)
#define LOG2E 1.4426950408889634f
static __device__ __forceinline__ float fast_sigmoid(float x) {
    float t = __builtin_amdgcn_exp2f(-x * LOG2E);
    return __builtin_amdgcn_rcpf(1.0f + t);
}
static __device__ __forceinline__ float fast_tanh(float x) {
    float t = __builtin_amdgcn_exp2f(x * (2.0f * LOG2E));
    return 1.0f - 2.0f * __builtin_amdgcn_rcpf(t + 1.0f);
}

// chunk-major layout helpers: buffer is [4][M][32] bf16 (chunk = col/32)
static __device__ __forceinline__ size_t amaj8(int gr, int c8, int M) {
    // c8 = index of bf16x8 group (0..15) within a 128-col row
    return ((size_t)(c8 >> 2) * M + gr) * 32 + ((c8 & 3) << 3);
}

// ---------------------------------------------------------------------------
// weight preconversion
// ---------------------------------------------------------------------------
__global__ void cvt_bf16_k(const float* __restrict__ in, short* __restrict__ out, int n) {
    int i = blockIdx.x * blockDim.x + threadIdx.x;
    if (i < n) out[i] = f2bf(in[i]);
}

__global__ void cvt_bf16_t_k(const float* __restrict__ in, short* __restrict__ out, int K, int N) {
    int i = blockIdx.x * blockDim.x + threadIdx.x;
    if (i >= K * N) return;
    int nn = i >> HBITS;
    int kk = i & (NODES_H - 1);
    out[i] = f2bf(in[kk * N + nn]);  // out[n][k] = in[k][n], K==128
}

// ---------------------------------------------------------------------------
// CSR build
// ---------------------------------------------------------------------------
__global__ void zero_cnt_k(int* __restrict__ cnt, int N) {
    int i = blockIdx.x * blockDim.x + threadIdx.x;
    if (i < N) cnt[i] = 0;
}

__global__ void count_k(const int* __restrict__ dst, int* __restrict__ cnt, int E) {
    int e = blockIdx.x * blockDim.x + threadIdx.x;
    if (e < E) atomicAdd(&cnt[dst[e]], 1);
}

__global__ __launch_bounds__(256) void scan1_k(const int* __restrict__ cnt,
                                               int* __restrict__ rowptr,
                                               int* __restrict__ bsum, int N) {
    __shared__ int buf[256];
    int tid = threadIdx.x;
    int i = blockIdx.x * 256 + tid;
    int v = (i < N) ? cnt[i] : 0;
    buf[tid] = v;
    __syncthreads();
#pragma unroll
    for (int off = 1; off < 256; off <<= 1) {
        int t = (tid >= off) ? buf[tid - off] : 0;
        __syncthreads();
        buf[tid] += t;
        __syncthreads();
    }
    if (i < N) rowptr[i] = buf[tid] - v;
    if (tid == 255) bsum[blockIdx.x] = buf[255];
}

__global__ __launch_bounds__(256) void scan2_k(int* __restrict__ bsum, int nb) {
    __shared__ int buf[256];
    int tid = threadIdx.x;
    int v = (tid < nb) ? bsum[tid] : 0;
    buf[tid] = v;
    __syncthreads();
#pragma unroll
    for (int off = 1; off < 256; off <<= 1) {
        int t = (tid >= off) ? buf[tid - off] : 0;
        __syncthreads();
        buf[tid] += t;
        __syncthreads();
    }
    if (tid < nb) bsum[tid] = buf[tid] - v;
}

__global__ void scan3_k(int* __restrict__ rowptr, const int* __restrict__ bsum,
                        const int* __restrict__ cnt, int* __restrict__ pos,
                        float* __restrict__ dis, int N, int E) {
    int i = blockIdx.x * blockDim.x + threadIdx.x;
    if (i < N) {
        int v = rowptr[i] + bsum[blockIdx.x];
        rowptr[i] = v;
        pos[i] = v;
        dis[i] = rsqrtf((float)(cnt[i] + 1));
    }
    if (i == 0) rowptr[N] = E;
}

__global__ void reorder_k(const int* __restrict__ src, const int* __restrict__ dst,
                          int* __restrict__ pos, int* __restrict__ csr_src, int E) {
    int e = blockIdx.x * blockDim.x + threadIdx.x;
    if (e >= E) return;
    int p = atomicAdd(&pos[dst[e]], 1);
    csr_src[p] = src[e];
}

// ---------------------------------------------------------------------------
// h init (bf16 state only, row-major)
// ---------------------------------------------------------------------------
__global__ void h_init_k(const float* __restrict__ hc, unsigned short* __restrict__ hb,
                         int total) {
    int i = blockIdx.x * blockDim.x + threadIdx.x;
    if (i < total) hb[i] = (unsigned short)f2bf(hc[i & (NODES_H - 1)]);
}

// ---------------------------------------------------------------------------
// fp32 tiled GEMM (proj: K=16), bf16 output, CHUNK-MAJOR C
// ---------------------------------------------------------------------------
#define BM 64
#define BN 64
#define BK 16

template <bool WT, bool RELU_A>
__global__ __launch_bounds__(256) void gemm_k(const float* __restrict__ A,
                                              const float* __restrict__ W,
                                              const float* __restrict__ bias,
                                              unsigned short* __restrict__ C,
                                              int M, int K, int N) {
    __shared__ float As[BK][BM + 1];
    __shared__ float Ws[BK][BN + 1];

    const int gn = N / BN;
    const int bx = blockIdx.x % gn;
    const int by = blockIdx.x / gn;
    const int tid = threadIdx.x;
    const int tx = tid & 15;
    const int ty = tid >> 4;
    const int row0 = by * BM;
    const int col0 = bx * BN;

    float acc[4][4] = {};

    for (int k0 = 0; k0 < K; k0 += BK) {
#pragma unroll
        for (int i = 0; i < 4; ++i) {
            int idx = tid + i * 256;
            int r = idx >> 4, k = idx & 15;
            int gr = row0 + r;
            float v = (gr < M) ? A[(size_t)gr * K + k0 + k] : 0.0f;
            if (RELU_A) v = fmaxf(v, 0.0f);
            As[k][r] = v;
        }
#pragma unroll
        for (int i = 0; i < 4; ++i) {
            int idx = tid + i * 256;
            if (!WT) {
                int k = idx >> 6, n = idx & 63;
                Ws[k][n] = W[(size_t)(k0 + k) * N + col0 + n];
            } else {
                int n = idx >> 4, k = idx & 15;
                Ws[k][n] = W[(size_t)(col0 + n) * K + k0 + k];
            }
        }
        __syncthreads();

#pragma unroll
        for (int kk = 0; kk < BK; ++kk) {
            float a[4], w[4];
#pragma unroll
            for (int i = 0; i < 4; ++i) a[i] = As[kk][ty * 4 + i];
#pragma unroll
            for (int j = 0; j < 4; ++j) w[j] = Ws[kk][tx * 4 + j];
#pragma unroll
            for (int i = 0; i < 4; ++i)
#pragma unroll
                for (int j = 0; j < 4; ++j) acc[i][j] += a[i] * w[j];
        }
        __syncthreads();
    }

#pragma unroll
    for (int i = 0; i < 4; ++i) {
        int gr = row0 + ty * 4 + i;
        if (gr >= M) continue;
#pragma unroll
        for (int j = 0; j < 4; ++j) {
            int gc = col0 + tx * 4 + j;
            float v = acc[i][j];
            if (bias) v += bias[gc];
            C[((size_t)(gc >> 5) * M + gr) * 32 + (gc & 31)] = (unsigned short)f2bf(v);
        }
    }
}

// ---------------------------------------------------------------------------
// MFMA helpers (R8 structure): 64-row tile.
// ---------------------------------------------------------------------------
struct BFrags2 { bf16x8 b[2][4]; };  // [n][ks]

static __device__ __forceinline__ void load_b2(const short* __restrict__ Wg,
                                               int c0, int lrow, int lk, BFrags2& f) {
#pragma unroll
    for (int n = 0; n < 2; ++n) {
        int cc = c0 + (n << 4) + lrow;
#pragma unroll
        for (int ks = 0; ks < 4; ++ks) {
            int chunk = (ks << 2) + lk;
            f.b[n][ks] = *(const bf16x8*)&Wg[((size_t)cc << 7) + (chunk << 3)];
        }
    }
}

static __device__ __forceinline__ void mfma_apply2(const short* __restrict__ S,
                                                   const BFrags2& f, int lrow, int lk,
                                                   f32x4 acc[4][2]) {
#pragma unroll
    for (int ks = 0; ks < 4; ++ks) {
        int chunk = (ks << 2) + lk;
        bf16x8 a[4];
#pragma unroll
        for (int m = 0; m < 4; ++m) {
            int rr = (m << 4) + lrow;
            a[m] = *(const bf16x8*)&S[rr * 128 + ((chunk ^ (rr & 7)) << 3)];
        }
#pragma unroll
        for (int m = 0; m < 4; ++m)
#pragma unroll
            for (int n = 0; n < 2; ++n)
                acc[m][n] = __builtin_amdgcn_mfma_f32_16x16x32_bf16(a[m], f.b[n][ks], acc[m][n], 0, 0, 0);
    }
}

// inline-B variant (conv), m2 x n4 split
static __device__ __forceinline__ void mfma_pass_g(const short* __restrict__ S,
                                                   const short* __restrict__ Wg,
                                                   int r0, int c0, int lrow, int lk,
                                                   f32x4 acc[2][4]) {
#pragma unroll
    for (int ks = 0; ks < 4; ++ks) {
        int chunk = (ks << 2) + lk;
        bf16x8 a[2], b[4];
#pragma unroll
        for (int m = 0; m < 2; ++m) {
            int rr = r0 + (m << 4) + lrow;
            a[m] = *(const bf16x8*)&S[rr * 128 + ((chunk ^ (rr & 7)) << 3)];
        }
#pragma unroll
        for (int n = 0; n < 4; ++n) {
            int cc = c0 + (n << 4) + lrow;
            b[n] = *(const bf16x8*)&Wg[((size_t)cc << 7) + (chunk << 3)];
        }
#pragma unroll
        for (int m = 0; m < 2; ++m)
#pragma unroll
            for (int n = 0; n < 4; ++n)
                acc[m][n] = __builtin_amdgcn_mfma_f32_16x16x32_bf16(a[m], b[n], acc[m][n], 0, 0, 0);
    }
}

// swizzled LDS read of one bf16 element (epilogue h reuse)
static __device__ __forceinline__ float lds_bf16(const short* __restrict__ S, int r, int c) {
    return bf2f((unsigned short)S[r * 128 + (((c >> 3) ^ (r & 7)) << 3) + (c & 7)]);
}

// ---------------------------------------------------------------------------
// bf16 MFMA GEMM (convs): C_chunkmajor = relu?(A) @ Wt^T. 64-row tile, m2 x n4.
// CHUNK_A: A is chunk-major [4][M][32]; else row-major [M][128].
// ---------------------------------------------------------------------------
template <bool RELU_A, bool CHUNK_A>
__global__ __launch_bounds__(256, 4) void gemm_mfma_k(const unsigned short* __restrict__ A,
                                                      const short* __restrict__ Wt,
                                                      unsigned short* __restrict__ C,
                                                      int M) {
    __shared__ short As[64 * 128];

    const int row0 = blockIdx.x << 6;
    const int tid = threadIdx.x;

#pragma unroll
    for (int i = 0; i < 4; ++i) {
        int idx = tid + (i << 8);
        int r = idx >> 4, c = idx & 15;
        int gr = row0 + r;
        bf16x8 t;
        if (gr < M) {
            size_t off = CHUNK_A ? amaj8(gr, c, M) : ((((size_t)gr) << 7) + (c << 3));
            t = *(const bf16x8*)(A + off);
            if (RELU_A) {
#pragma unroll
                for (int j = 0; j < 8; ++j) {
                    unsigned short u = (unsigned short)t[j];
                    t[j] = (short)((u & 0x8000u) ? 0 : u);
                }
            }
        } else {
#pragma unroll
            for (int j = 0; j < 8; ++j) t[j] = 0;
        }
        *(bf16x8*)&As[r * 128 + ((c ^ (r & 7)) << 3)] = t;
    }
    __syncthreads();

    const int lane = tid & 63;
    const int wid = tid >> 6;
    const int r0 = (wid >> 1) << 5;
    const int c0 = (wid & 1) << 6;
    const int lrow = lane & 15;
    const int lk = lane >> 4;

    f32x4 acc[2][4] = {};
    mfma_pass_g(As, Wt, r0, c0, lrow, lk, acc);

    // chunk-major store, n innermost (n pairs land 32B-contiguous per chunk)
#pragma unroll
    for (int m = 0; m < 2; ++m) {
#pragma unroll
        for (int j = 0; j < 4; ++j) {
            int gr = row0 + r0 + (m << 4) + (lk << 2) + j;
            if (gr >= M) continue;
#pragma unroll
            for (int n = 0; n < 4; ++n) {
                int gc = c0 + (n << 4) + lrow;
                C[((size_t)(gc >> 5) * M + gr) * 32 + (gc & 31)] = (unsigned short)f2bf(acc[m][n][j]);
            }
        }
    }
}

// ---------------------------------------------------------------------------
// Fused GRU (R8 structure: 64-row tile, m4 x n2, single B reg-buffer, direct
// stores). A is CHUNK-MAJOR; hb/hnb row-major.
// ---------------------------------------------------------------------------
template <bool RELU_A>
__global__ __launch_bounds__(256, 3) void gru_fused_k(const unsigned short* __restrict__ A,
                                                      const unsigned short* __restrict__ hb,
                                                      const short* __restrict__ WihT,
                                                      const short* __restrict__ WhhT,
                                                      const float* __restrict__ bih,
                                                      const float* __restrict__ bhh,
                                                      unsigned short* __restrict__ hnb,
                                                      int M) {
    __shared__ short As[64 * 128];
    __shared__ short Hs[64 * 128];

    const int row0 = blockIdx.x << 6;
    const int tid = threadIdx.x;

#pragma unroll
    for (int i = 0; i < 4; ++i) {
        int idx = tid + (i << 8);
        int r = idx >> 4, c = idx & 15;
        int gr = row0 + r;
        bf16x8 ta, th;
        if (gr < M) {
            ta = *(const bf16x8*)(A + amaj8(gr, c, M));
            if (RELU_A) {
#pragma unroll
                for (int j = 0; j < 8; ++j) {
                    unsigned short u = (unsigned short)ta[j];
                    ta[j] = (short)((u & 0x8000u) ? 0 : u);
                }
            }
            th = *(const bf16x8*)(hb + (((size_t)gr) << 7) + (c << 3));
        } else {
#pragma unroll
            for (int j = 0; j < 8; ++j) { ta[j] = 0; th[j] = 0; }
        }
        int sw = r * 128 + ((c ^ (r & 7)) << 3);
        *(bf16x8*)&As[sw] = ta;
        *(bf16x8*)&Hs[sw] = th;
    }

    const int lane = tid & 63;
    const int wid = tid >> 6;
    const int c0 = wid << 5;
    const int lrow = lane & 15;
    const int lk = lane >> 4;

    float br[2], bz[2], bni[2], bnh[2];
#pragma unroll
    for (int n = 0; n < 2; ++n) {
        int gc = c0 + (n << 4) + lrow;
        br[n] = bih[gc] + bhh[gc];
        bz[n] = bih[128 + gc] + bhh[128 + gc];
        bni[n] = bih[256 + gc];
        bnh[n] = bhh[256 + gc];
    }

    const int GS = 128 * 128;
    BFrags2 bf;
    load_b2(WihT, c0, lrow, lk, bf);
    __syncthreads();

    f32x4 accR[4][2] = {};
    f32x4 accT[4][2] = {};

    mfma_apply2(As, bf, lrow, lk, accR);            // gi_r
    load_b2(WhhT, c0, lrow, lk, bf);
    mfma_apply2(Hs, bf, lrow, lk, accR);            // + gh_r
    load_b2(WhhT + 2 * GS, c0, lrow, lk, bf);
    mfma_apply2(Hs, bf, lrow, lk, accT);            // gh_n

#pragma unroll
    for (int m = 0; m < 4; ++m)
#pragma unroll
        for (int n = 0; n < 2; ++n)
#pragma unroll
            for (int j = 0; j < 4; ++j) {
                float rr = fast_sigmoid(accR[m][n][j] + br[n]);
                accT[m][n][j] = rr * (accT[m][n][j] + bnh[n]);
            }

    load_b2(WihT + 2 * GS, c0, lrow, lk, bf);
    mfma_apply2(As, bf, lrow, lk, accT);            // += gi_n

#pragma unroll
    for (int m = 0; m < 4; ++m)
#pragma unroll
        for (int n = 0; n < 2; ++n)
#pragma unroll
            for (int j = 0; j < 4; ++j)
                accT[m][n][j] = fast_tanh(accT[m][n][j] + bni[n]);

    f32x4 accZ[4][2] = {};
    load_b2(WihT + GS, c0, lrow, lk, bf);
    mfma_apply2(As, bf, lrow, lk, accZ);            // gi_z
    load_b2(WhhT + GS, c0, lrow, lk, bf);
    mfma_apply2(Hs, bf, lrow, lk, accZ);            // + gh_z

    // epilogue: z, h' = (1-z)*n + z*h ; direct row-major stores
#pragma unroll
    for (int m = 0; m < 4; ++m) {
#pragma unroll
        for (int j = 0; j < 4; ++j) {
            int lr = (m << 4) + (lk << 2) + j;
            int grow = row0 + lr;
            if (grow >= M) continue;
#pragma unroll
            for (int n = 0; n < 2; ++n) {
                int gcol = c0 + (n << 4) + lrow;
                float zz = fast_sigmoid(accZ[m][n][j] + bz[n]);
                float hv = lds_bf16(Hs, lr, gcol);
                float v = (1.0f - zz) * accT[m][n][j] + zz * hv;
                hnb[((size_t)grow << 7) + gcol] = (unsigned short)f2bf(v);
            }
        }
    }
}

// ---------------------------------------------------------------------------
// GCN gather, chunked: HW and out are chunk-major [4][N][32].
// One wave = 4 nodes x 16 lanes; per chunk the HW slice (3.2 MB) is
// L2-resident, so the random per-edge 64B reads hit L2.
// out[d] = dd*(dd*HW[d] + sum_e dis[s]*HW[s]) + bias
// ---------------------------------------------------------------------------
__global__ __launch_bounds__(256) void gcn_gather_k(const unsigned short* __restrict__ HWt,
                                                    const float* __restrict__ dis,
                                                    const int* __restrict__ rowptr,
                                                    const int* __restrict__ csr_src,
                                                    const float* __restrict__ bias,
                                                    unsigned short* __restrict__ outt,
                                                    int Nn, int G) {
    int wave = blockIdx.x * 4 + (threadIdx.x >> 6);
    int chunk = wave / G;
    int g = wave - chunk * G;
    if (chunk >= 4) return;
    int lane = threadIdx.x & 63;
    int node = (g << 2) + (lane >> 4);
    if (node >= Nn) return;
    int cl = (lane & 15) << 1;  // col pair within chunk

    const unsigned short* HWc = HWt + (size_t)chunk * Nn * 32;
    float dd = dis[node];
    unsigned v0 = *(const unsigned*)&HWc[(size_t)node * 32 + cl];
    float2 b2 = *(const float2*)&bias[(chunk << 5) + cl];
    float accx = bf2f((unsigned short)(v0 & 0xFFFFu)) * dd;
    float accy = bf2f((unsigned short)(v0 >> 16)) * dd;

    int e = rowptr[node], end = rowptr[node + 1];
    for (; e + 1 < end; e += 2) {
        int s0 = csr_src[e], s1 = csr_src[e + 1];
        float w0 = dis[s0], w1 = dis[s1];
        unsigned a = *(const unsigned*)&HWc[(size_t)s0 * 32 + cl];
        unsigned b = *(const unsigned*)&HWc[(size_t)s1 * 32 + cl];
        accx += bf2f((unsigned short)(a & 0xFFFFu)) * w0;
        accy += bf2f((unsigned short)(a >> 16)) * w0;
        accx += bf2f((unsigned short)(b & 0xFFFFu)) * w1;
        accy += bf2f((unsigned short)(b >> 16)) * w1;
    }
    if (e < end) {
        int s = csr_src[e];
        float w = dis[s];
        unsigned a = *(const unsigned*)&HWc[(size_t)s * 32 + cl];
        accx += bf2f((unsigned short)(a & 0xFFFFu)) * w;
        accy += bf2f((unsigned short)(a >> 16)) * w;
    }
    accx = accx * dd + b2.x;
    accy = accy * dd + b2.y;
    unsigned o = ((unsigned)(unsigned short)f2bf(accy) << 16) | (unsigned short)f2bf(accx);
    *(unsigned*)&outt[((size_t)chunk * Nn + node) * 32 + cl] = o;
}

// ---------------------------------------------------------------------------
// Output head (bf16 h input, row-major)
// ---------------------------------------------------------------------------
#define OUT_DIM 5
__global__ void out_softmax_k(const unsigned short* __restrict__ h,
                              const float* __restrict__ Wo,
                              const float* __restrict__ bo, float* __restrict__ out, int N) {
    int gtid = blockIdx.x * blockDim.x + threadIdx.x;
    int node = gtid >> 6;
    int lane = threadIdx.x & 63;
    if (node >= N) return;
    const unsigned short* hr = h + ((size_t)node << HBITS);
    float h0 = bf2f(hr[lane]);
    float h1 = bf2f(hr[lane + 64]);
    float acc[OUT_DIM];
#pragma unroll
    for (int o = 0; o < OUT_DIM; ++o)
        acc[o] = h0 * Wo[lane * OUT_DIM + o] + h1 * Wo[(lane + 64) * OUT_DIM + o];
#pragma unroll
    for (int off = 32; off >= 1; off >>= 1) {
#pragma unroll
        for (int o = 0; o < OUT_DIM; ++o) acc[o] += __shfl_down(acc[o], off, 64);
    }
    if (lane == 0) {
        float v[OUT_DIM], m = -1e30f;
#pragma unroll
        for (int o = 0; o < OUT_DIM; ++o) { v[o] = acc[o] + bo[o]; m = fmaxf(m, v[o]); }
        float s = 0.0f;
#pragma unroll
        for (int o = 0; o < OUT_DIM; ++o) { v[o] = __builtin_amdgcn_exp2f((v[o] - m) * LOG2E); s += v[o]; }
        float inv = 1.0f / s;
#pragma unroll
        for (int o = 0; o < OUT_DIM; ++o) out[(size_t)node * OUT_DIM + o] = v[o] * inv;
    }
}

// ---------------------------------------------------------------------------
// launch
// ---------------------------------------------------------------------------
static inline int cdiv(long long a, long long b) { return (int)((a + b - 1) / b); }
static inline char* align256(char* p) {
    return (char*)(((uintptr_t)p + 255) & ~(uintptr_t)255);
}

extern "C" void kernel_launch(void* const* d_in, const int* in_sizes, int n_in,
                              void* d_out, int out_size, void* d_ws, size_t ws_size,
                              hipStream_t stream) {
    const float* x       = (const float*)d_in[0];
    const int*   eidx    = (const int*)d_in[1];
    const float* proj_W  = (const float*)d_in[2];
    const float* proj_b  = (const float*)d_in[3];
    const float* conv1_W = (const float*)d_in[4];
    const float* conv1_b = (const float*)d_in[5];
    const float* conv2_W = (const float*)d_in[6];
    const float* conv2_b = (const float*)d_in[7];
    const float* hidden_c= (const float*)d_in[8];
    const float* gru_Wih = (const float*)d_in[9];
    const float* gru_Whh = (const float*)d_in[10];
    const float* gru_bih = (const float*)d_in[11];
    const float* gru_bhh = (const float*)d_in[12];
    const float* out_W   = (const float*)d_in[13];
    const float* out_b   = (const float*)d_in[14];
    float* out = (float*)d_out;

    const int F = 16, H = 128, G3 = 384;
    const int N = in_sizes[0] / F;
    const int E = in_sizes[1] / 2;
    const int* src = eidx;
    const int* dst = eidx + E;

    const int TPB = 256;
    const int nScanBlocks = cdiv(N, 256);

    // workspace (256B-aligned slots)
    char* wp = (char*)d_ws;
#define ALLOC(ptr_t, name, bytes) ptr_t name = (ptr_t)wp; wp = align256(wp + (bytes))
    ALLOC(int*, cnt, (size_t)N * 4);
    ALLOC(int*, rowptr, (size_t)(N + 1) * 4);
    ALLOC(int*, pos, (size_t)N * 4);
    ALLOC(int*, bsum, 256 * 4);
    ALLOC(int*, csr_src, (size_t)E * 4);
    ALLOC(float*, dis, (size_t)N * 4);
    ALLOC(short*, c1Wt, (size_t)H * H * 2);
    ALLOC(short*, c2Wt, (size_t)H * H * 2);
    ALLOC(short*, WihT, (size_t)G3 * H * 2);
    ALLOC(short*, WhhT, (size_t)G3 * H * 2);
    ALLOC(unsigned short*, h0b, (size_t)N * H * 2);
    ALLOC(unsigned short*, h1b, (size_t)N * H * 2);
    ALLOC(unsigned short*, Abuf, (size_t)N * H * 2);   // chunk-major [4][N][32]
    ALLOC(unsigned short*, HWb, (size_t)N * H * 2);    // chunk-major [4][N][32]
#undef ALLOC

    const int totNH = N * H;

    // --- weight preconversion (bf16, [n][k]) ---
    cvt_bf16_t_k<<<cdiv(H * H, TPB), TPB, 0, stream>>>(conv1_W, c1Wt, H, H);
    cvt_bf16_t_k<<<cdiv(H * H, TPB), TPB, 0, stream>>>(conv2_W, c2Wt, H, H);
    cvt_bf16_k<<<cdiv(G3 * H, TPB), TPB, 0, stream>>>(gru_Wih, WihT, G3 * H);
    cvt_bf16_k<<<cdiv(G3 * H, TPB), TPB, 0, stream>>>(gru_Whh, WhhT, G3 * H);

    // --- CSR build + normalization ---
    zero_cnt_k<<<cdiv(N, TPB), TPB, 0, stream>>>(cnt, N);
    count_k<<<cdiv(E, TPB), TPB, 0, stream>>>(dst, cnt, E);
    scan1_k<<<nScanBlocks, 256, 0, stream>>>(cnt, rowptr, bsum, N);
    scan2_k<<<1, 256, 0, stream>>>(bsum, nScanBlocks);
    scan3_k<<<nScanBlocks, 256, 0, stream>>>(rowptr, bsum, cnt, pos, dis, N, E);
    reorder_k<<<cdiv(E, TPB), TPB, 0, stream>>>(src, dst, pos, csr_src, E);

    // --- h init (bf16, row-major) ---
    h_init_k<<<cdiv(totNH, TPB), TPB, 0, stream>>>(hidden_c, h0b, totNH);

    unsigned short* hb_cur = h0b;
    unsigned short* hb_nxt = h1b;

    const int gm64 = cdiv(N, 64);
    const int Ggather = cdiv(N, 4);          // node-groups per chunk
    const int gatherBlocks = Ggather;        // 4 waves/block x (4 chunks x G waves) / 4

    // --- proj (K=16, fp32 path, chunk-major bf16 out) ---
    dim3 gridP(cdiv(N, BM) * (H / BN));
    gemm_k<false, false><<<gridP, TPB, 0, stream>>>(x, proj_W, proj_b, Abuf, N, F, H);

    // --- GRU step 0 (fused; A chunk-major) ---
    gru_fused_k<false><<<gm64, TPB, 0, stream>>>(Abuf, hb_cur, WihT, WhhT,
                                                 gru_bih, gru_bhh, hb_nxt, N);
    { unsigned short* t = hb_cur; hb_cur = hb_nxt; hb_nxt = t; }

    for (int it = 0; it < 3; ++it) {
        gemm_mfma_k<false, false><<<gm64, TPB, 0, stream>>>(hb_cur, c1Wt, HWb, N);
        gcn_gather_k<<<gatherBlocks, TPB, 0, stream>>>(HWb, dis, rowptr, csr_src,
                                                       conv1_b, Abuf, N, Ggather);
        gemm_mfma_k<true, true><<<gm64, TPB, 0, stream>>>(Abuf, c2Wt, HWb, N);
        gcn_gather_k<<<gatherBlocks, TPB, 0, stream>>>(HWb, dis, rowptr, csr_src,
                                                       conv2_b, Abuf, N, Ggather);
        gru_fused_k<true><<<gm64, TPB, 0, stream>>>(Abuf, hb_cur, WihT, WhhT,
                                                    gru_bih, gru_bhh, hb_nxt, N);
        { unsigned short* t = hb_cur; hb_cur = hb_nxt; hb_nxt = t; }
    }

    // --- output head ---
    out_softmax_k<<<cdiv((long long)N * 64, TPB), TPB, 0, stream>>>(hb_cur, out_W, out_b, out, N);
}

// Round 12
// 728.933 us; speedup vs baseline: 1.0920x; 1.0920x over previous
//
#include <hip/hip_runtime.h>
#include <hip/hip_bf16.h>

#define NODES_H 128
#define HBITS 7   // 128 = 1<<7

typedef __attribute__((ext_vector_type(8))) short bf16x8;
typedef __attribute__((ext_vector_type(4))) float f32x4;

static __device__ __forceinline__ short f2bf(float f) {
    union { float f; unsigned u; } v; v.f = f;
    unsigned r = v.u + 0x7FFFu + ((v.u >> 16) & 1u);  // RNE
    return (short)(r >> 16);
}
static __device__ __forceinline__ float bf2f(unsigned short u) {
    union { unsigned u; float f; } v; v.u = ((unsigned)u) << 16;
    return v.f;
}
// fast sigmoid/tanh via native v_exp_f32 (2^x) + v_rcp_f32 (~1 ulp)
#define LOG2E 1.4426950408889634f
static __device__ __forceinline__ float fast_sigmoid(float x) {
    float t = __builtin_amdgcn_exp2f(-x * LOG2E);
    return __builtin_amdgcn_rcpf(1.0f + t);
}
static __device__ __forceinline__ float fast_tanh(float x) {
    float t = __builtin_amdgcn_exp2f(x * (2.0f * LOG2E));
    return 1.0f - 2.0f * __builtin_amdgcn_rcpf(t + 1.0f);
}

// ---------------------------------------------------------------------------
// weight preconversion
// ---------------------------------------------------------------------------
__global__ void cvt_bf16_k(const float* __restrict__ in, short* __restrict__ out, int n) {
    int i = blockIdx.x * blockDim.x + threadIdx.x;
    if (i < n) out[i] = f2bf(in[i]);
}

__global__ void cvt_bf16_t_k(const float* __restrict__ in, short* __restrict__ out, int K, int N) {
    int i = blockIdx.x * blockDim.x + threadIdx.x;
    if (i >= K * N) return;
    int nn = i >> HBITS;
    int kk = i & (NODES_H - 1);
    out[i] = f2bf(in[kk * N + nn]);  // out[n][k] = in[k][n], K==128
}

// ---------------------------------------------------------------------------
// CSR build
// ---------------------------------------------------------------------------
__global__ void zero_cnt_k(int* __restrict__ cnt, int N) {
    int i = blockIdx.x * blockDim.x + threadIdx.x;
    if (i < N) cnt[i] = 0;
}

__global__ void count_k(const int* __restrict__ dst, int* __restrict__ cnt, int E) {
    int e = blockIdx.x * blockDim.x + threadIdx.x;
    if (e < E) atomicAdd(&cnt[dst[e]], 1);
}

__global__ __launch_bounds__(256) void scan1_k(const int* __restrict__ cnt,
                                               int* __restrict__ rowptr,
                                               int* __restrict__ bsum, int N) {
    __shared__ int buf[256];
    int tid = threadIdx.x;
    int i = blockIdx.x * 256 + tid;
    int v = (i < N) ? cnt[i] : 0;
    buf[tid] = v;
    __syncthreads();
#pragma unroll
    for (int off = 1; off < 256; off <<= 1) {
        int t = (tid >= off) ? buf[tid - off] : 0;
        __syncthreads();
        buf[tid] += t;
        __syncthreads();
    }
    if (i < N) rowptr[i] = buf[tid] - v;
    if (tid == 255) bsum[blockIdx.x] = buf[255];
}

__global__ __launch_bounds__(256) void scan2_k(int* __restrict__ bsum, int nb) {
    __shared__ int buf[256];
    int tid = threadIdx.x;
    int v = (tid < nb) ? bsum[tid] : 0;
    buf[tid] = v;
    __syncthreads();
#pragma unroll
    for (int off = 1; off < 256; off <<= 1) {
        int t = (tid >= off) ? buf[tid - off] : 0;
        __syncthreads();
        buf[tid] += t;
        __syncthreads();
    }
    if (tid < nb) bsum[tid] = buf[tid] - v;
}

__global__ void scan3_k(int* __restrict__ rowptr, const int* __restrict__ bsum,
                        const int* __restrict__ cnt, int* __restrict__ pos,
                        float* __restrict__ dis, int N, int E) {
    int i = blockIdx.x * blockDim.x + threadIdx.x;
    if (i < N) {
        int v = rowptr[i] + bsum[blockIdx.x];
        rowptr[i] = v;
        pos[i] = v;
        dis[i] = rsqrtf((float)(cnt[i] + 1));
    }
    if (i == 0) rowptr[N] = E;
}

__global__ void reorder_k(const int* __restrict__ src, const int* __restrict__ dst,
                          int* __restrict__ pos, int* __restrict__ csr_src, int E) {
    int e = blockIdx.x * blockDim.x + threadIdx.x;
    if (e >= E) return;
    int p = atomicAdd(&pos[dst[e]], 1);
    csr_src[p] = src[e];
}

// ---------------------------------------------------------------------------
// h init (bf16 state only)
// ---------------------------------------------------------------------------
__global__ void h_init_k(const float* __restrict__ hc, unsigned short* __restrict__ hb,
                         int total) {
    int i = blockIdx.x * blockDim.x + threadIdx.x;
    if (i < total) hb[i] = (unsigned short)f2bf(hc[i & (NODES_H - 1)]);
}

// ---------------------------------------------------------------------------
// fp32 tiled GEMM (proj: K=16), bf16 output (row-major)
// ---------------------------------------------------------------------------
#define BM 64
#define BN 64
#define BK 16

template <bool WT, bool RELU_A>
__global__ __launch_bounds__(256) void gemm_k(const float* __restrict__ A,
                                              const float* __restrict__ W,
                                              const float* __restrict__ bias,
                                              unsigned short* __restrict__ C,
                                              int M, int K, int N) {
    __shared__ float As[BK][BM + 1];
    __shared__ float Ws[BK][BN + 1];

    const int gn = N / BN;
    const int bx = blockIdx.x % gn;
    const int by = blockIdx.x / gn;
    const int tid = threadIdx.x;
    const int tx = tid & 15;
    const int ty = tid >> 4;
    const int row0 = by * BM;
    const int col0 = bx * BN;

    float acc[4][4] = {};

    for (int k0 = 0; k0 < K; k0 += BK) {
#pragma unroll
        for (int i = 0; i < 4; ++i) {
            int idx = tid + i * 256;
            int r = idx >> 4, k = idx & 15;
            int gr = row0 + r;
            float v = (gr < M) ? A[(size_t)gr * K + k0 + k] : 0.0f;
            if (RELU_A) v = fmaxf(v, 0.0f);
            As[k][r] = v;
        }
#pragma unroll
        for (int i = 0; i < 4; ++i) {
            int idx = tid + i * 256;
            if (!WT) {
                int k = idx >> 6, n = idx & 63;
                Ws[k][n] = W[(size_t)(k0 + k) * N + col0 + n];
            } else {
                int n = idx >> 4, k = idx & 15;
                Ws[k][n] = W[(size_t)(col0 + n) * K + k0 + k];
            }
        }
        __syncthreads();

#pragma unroll
        for (int kk = 0; kk < BK; ++kk) {
            float a[4], w[4];
#pragma unroll
            for (int i = 0; i < 4; ++i) a[i] = As[kk][ty * 4 + i];
#pragma unroll
            for (int j = 0; j < 4; ++j) w[j] = Ws[kk][tx * 4 + j];
#pragma unroll
            for (int i = 0; i < 4; ++i)
#pragma unroll
                for (int j = 0; j < 4; ++j) acc[i][j] += a[i] * w[j];
        }
        __syncthreads();
    }

#pragma unroll
    for (int i = 0; i < 4; ++i) {
        int gr = row0 + ty * 4 + i;
        if (gr >= M) continue;
#pragma unroll
        for (int j = 0; j < 4; ++j) {
            int gc = col0 + tx * 4 + j;
            float v = acc[i][j];
            if (bias) v += bias[gc];
            C[(size_t)gr * N + gc] = (unsigned short)f2bf(v);
        }
    }
}

// ---------------------------------------------------------------------------
// MFMA helpers, 64-row tile.
// ---------------------------------------------------------------------------
struct BFrags2 { bf16x8 b[2][4]; };  // [n][ks]

static __device__ __forceinline__ void load_b2(const short* __restrict__ Wg,
                                               int c0, int lrow, int lk, BFrags2& f) {
#pragma unroll
    for (int n = 0; n < 2; ++n) {
        int cc = c0 + (n << 4) + lrow;
#pragma unroll
        for (int ks = 0; ks < 4; ++ks) {
            int chunk = (ks << 2) + lk;
            f.b[n][ks] = *(const bf16x8*)&Wg[((size_t)cc << 7) + (chunk << 3)];
        }
    }
}

static __device__ __forceinline__ void mfma_apply2(const short* __restrict__ S,
                                                   const BFrags2& f, int lrow, int lk,
                                                   f32x4 acc[4][2]) {
#pragma unroll
    for (int ks = 0; ks < 4; ++ks) {
        int chunk = (ks << 2) + lk;
        bf16x8 a[4];
#pragma unroll
        for (int m = 0; m < 4; ++m) {
            int rr = (m << 4) + lrow;
            a[m] = *(const bf16x8*)&S[rr * 128 + ((chunk ^ (rr & 7)) << 3)];
        }
#pragma unroll
        for (int m = 0; m < 4; ++m)
#pragma unroll
            for (int n = 0; n < 2; ++n)
                acc[m][n] = __builtin_amdgcn_mfma_f32_16x16x32_bf16(a[m], f.b[n][ks], acc[m][n], 0, 0, 0);
    }
}

// inline-B variant (conv), m2 x n4 split (full 128B line per wave-row)
static __device__ __forceinline__ void mfma_pass_g(const short* __restrict__ S,
                                                   const short* __restrict__ Wg,
                                                   int r0, int c0, int lrow, int lk,
                                                   f32x4 acc[2][4]) {
#pragma unroll
    for (int ks = 0; ks < 4; ++ks) {
        int chunk = (ks << 2) + lk;
        bf16x8 a[2], b[4];
#pragma unroll
        for (int m = 0; m < 2; ++m) {
            int rr = r0 + (m << 4) + lrow;
            a[m] = *(const bf16x8*)&S[rr * 128 + ((chunk ^ (rr & 7)) << 3)];
        }
#pragma unroll
        for (int n = 0; n < 4; ++n) {
            int cc = c0 + (n << 4) + lrow;
            b[n] = *(const bf16x8*)&Wg[((size_t)cc << 7) + (chunk << 3)];
        }
#pragma unroll
        for (int m = 0; m < 2; ++m)
#pragma unroll
            for (int n = 0; n < 4; ++n)
                acc[m][n] = __builtin_amdgcn_mfma_f32_16x16x32_bf16(a[m], b[n], acc[m][n], 0, 0, 0);
    }
}

// swizzled LDS read of one bf16 element (epilogue h reuse)
static __device__ __forceinline__ float lds_bf16(const short* __restrict__ S, int r, int c) {
    return bf2f((unsigned short)S[r * 128 + (((c >> 3) ^ (r & 7)) << 3) + (c & 7)]);
}

// ---------------------------------------------------------------------------
// bf16 MFMA GEMM (convs): C = relu?(A) @ Wt^T, bf16 out. K=N=128, 64-row tile,
// m2 x n4 wave split, n-innermost full-line stores.
// ---------------------------------------------------------------------------
template <bool RELU_A>
__global__ __launch_bounds__(256, 4) void gemm_mfma_k(const unsigned short* __restrict__ A,
                                                      const short* __restrict__ Wt,
                                                      unsigned short* __restrict__ C,
                                                      int M) {
    __shared__ short As[64 * 128];

    const int row0 = blockIdx.x << 6;
    const int tid = threadIdx.x;

#pragma unroll
    for (int i = 0; i < 4; ++i) {
        int idx = tid + (i << 8);
        int r = idx >> 4, c = idx & 15;
        int gr = row0 + r;
        bf16x8 t;
        if (gr < M) {
            t = *(const bf16x8*)(A + (((size_t)gr) << 7) + (c << 3));
            if (RELU_A) {
#pragma unroll
                for (int j = 0; j < 8; ++j) {
                    unsigned short u = (unsigned short)t[j];
                    t[j] = (short)((u & 0x8000u) ? 0 : u);
                }
            }
        } else {
#pragma unroll
            for (int j = 0; j < 8; ++j) t[j] = 0;
        }
        *(bf16x8*)&As[r * 128 + ((c ^ (r & 7)) << 3)] = t;
    }
    __syncthreads();

    const int lane = tid & 63;
    const int wid = tid >> 6;
    const int r0 = (wid >> 1) << 5;
    const int c0 = (wid & 1) << 6;
    const int lrow = lane & 15;
    const int lk = lane >> 4;

    f32x4 acc[2][4] = {};
    mfma_pass_g(As, Wt, r0, c0, lrow, lk, acc);

#pragma unroll
    for (int m = 0; m < 2; ++m) {
#pragma unroll
        for (int j = 0; j < 4; ++j) {
            int gr = row0 + r0 + (m << 4) + (lk << 2) + j;
            if (gr >= M) continue;
#pragma unroll
            for (int n = 0; n < 4; ++n) {
                int gc = c0 + (n << 4) + lrow;
                C[((size_t)gr << 7) + gc] = (unsigned short)f2bf(acc[m][n][j]);
            }
        }
    }
}

// ---------------------------------------------------------------------------
// Fused GRU (R8 known-best: 64-row tile, m4 x n2, single B reg-buffer, fast
// gate math, direct stores).
// ---------------------------------------------------------------------------
template <bool RELU_A>
__global__ __launch_bounds__(256, 3) void gru_fused_k(const unsigned short* __restrict__ A,
                                                      const unsigned short* __restrict__ hb,
                                                      const short* __restrict__ WihT,
                                                      const short* __restrict__ WhhT,
                                                      const float* __restrict__ bih,
                                                      const float* __restrict__ bhh,
                                                      unsigned short* __restrict__ hnb,
                                                      int M) {
    __shared__ short As[64 * 128];
    __shared__ short Hs[64 * 128];

    const int row0 = blockIdx.x << 6;
    const int tid = threadIdx.x;

#pragma unroll
    for (int i = 0; i < 4; ++i) {
        int idx = tid + (i << 8);
        int r = idx >> 4, c = idx & 15;
        int gr = row0 + r;
        bf16x8 ta, th;
        if (gr < M) {
            ta = *(const bf16x8*)(A + (((size_t)gr) << 7) + (c << 3));
            if (RELU_A) {
#pragma unroll
                for (int j = 0; j < 8; ++j) {
                    unsigned short u = (unsigned short)ta[j];
                    ta[j] = (short)((u & 0x8000u) ? 0 : u);
                }
            }
            th = *(const bf16x8*)(hb + (((size_t)gr) << 7) + (c << 3));
        } else {
#pragma unroll
            for (int j = 0; j < 8; ++j) { ta[j] = 0; th[j] = 0; }
        }
        int sw = r * 128 + ((c ^ (r & 7)) << 3);
        *(bf16x8*)&As[sw] = ta;
        *(bf16x8*)&Hs[sw] = th;
    }

    const int lane = tid & 63;
    const int wid = tid >> 6;
    const int c0 = wid << 5;
    const int lrow = lane & 15;
    const int lk = lane >> 4;

    float br[2], bz[2], bni[2], bnh[2];
#pragma unroll
    for (int n = 0; n < 2; ++n) {
        int gc = c0 + (n << 4) + lrow;
        br[n] = bih[gc] + bhh[gc];
        bz[n] = bih[128 + gc] + bhh[128 + gc];
        bni[n] = bih[256 + gc];
        bnh[n] = bhh[256 + gc];
    }

    const int GS = 128 * 128;
    BFrags2 bf;
    load_b2(WihT, c0, lrow, lk, bf);
    __syncthreads();

    f32x4 accR[4][2] = {};
    f32x4 accT[4][2] = {};

    mfma_apply2(As, bf, lrow, lk, accR);            // gi_r
    load_b2(WhhT, c0, lrow, lk, bf);
    mfma_apply2(Hs, bf, lrow, lk, accR);            // + gh_r
    load_b2(WhhT + 2 * GS, c0, lrow, lk, bf);
    mfma_apply2(Hs, bf, lrow, lk, accT);            // gh_n

#pragma unroll
    for (int m = 0; m < 4; ++m)
#pragma unroll
        for (int n = 0; n < 2; ++n)
#pragma unroll
            for (int j = 0; j < 4; ++j) {
                float rr = fast_sigmoid(accR[m][n][j] + br[n]);
                accT[m][n][j] = rr * (accT[m][n][j] + bnh[n]);
            }

    load_b2(WihT + 2 * GS, c0, lrow, lk, bf);
    mfma_apply2(As, bf, lrow, lk, accT);            // += gi_n

#pragma unroll
    for (int m = 0; m < 4; ++m)
#pragma unroll
        for (int n = 0; n < 2; ++n)
#pragma unroll
            for (int j = 0; j < 4; ++j)
                accT[m][n][j] = fast_tanh(accT[m][n][j] + bni[n]);

    f32x4 accZ[4][2] = {};
    load_b2(WihT + GS, c0, lrow, lk, bf);
    mfma_apply2(As, bf, lrow, lk, accZ);            // gi_z
    load_b2(WhhT + GS, c0, lrow, lk, bf);
    mfma_apply2(Hs, bf, lrow, lk, accZ);            // + gh_z

    // epilogue: z, h' = (1-z)*n + z*h
#pragma unroll
    for (int m = 0; m < 4; ++m) {
#pragma unroll
        for (int j = 0; j < 4; ++j) {
            int lr = (m << 4) + (lk << 2) + j;
            int grow = row0 + lr;
            if (grow >= M) continue;
#pragma unroll
            for (int n = 0; n < 2; ++n) {
                int gcol = c0 + (n << 4) + lrow;
                float zz = fast_sigmoid(accZ[m][n][j] + bz[n]);
                float hv = lds_bf16(Hs, lr, gcol);
                float v = (1.0f - zz) * accT[m][n][j] + zz * hv;
                hnb[((size_t)grow << 7) + gcol] = (unsigned short)f2bf(v);
            }
        }
    }
}

// ---------------------------------------------------------------------------
// GCN gather (pull): TWO waves per destination node. Each wave takes a
// contiguous half of the edge list (4-unrolled -> ~2 dependent load batches
// at deg~16), partials combined through LDS with one barrier.
// out[d] = dd*(dd*HW[d] + sum_e dis[s]*HW[s]) + bias  (bf16 rows, row-major)
// ---------------------------------------------------------------------------
__global__ __launch_bounds__(256) void gcn_gather_k(const unsigned short* __restrict__ HW,
                                                    const float* __restrict__ dis,
                                                    const int* __restrict__ rowptr,
                                                    const int* __restrict__ csr_src,
                                                    const float* __restrict__ bias,
                                                    unsigned short* __restrict__ out, int N) {
    __shared__ float2 part[2][64];
    const int tid = threadIdx.x;
    const int slot = tid >> 7;        // node within block (0..1)
    const int half = (tid >> 6) & 1;  // which wave of the pair
    const int lane = tid & 63;
    const int node = blockIdx.x * 2 + slot;
    const bool valid = node < N;

    float accx = 0.0f, accy = 0.0f;
    if (valid) {
        int beg = rowptr[node], end = rowptr[node + 1];
        int mid = beg + ((end - beg + 1) >> 1);
        int e = half ? mid : beg;
        int stop = half ? end : mid;
        for (; e + 3 < stop; e += 4) {
            int s0 = csr_src[e], s1 = csr_src[e + 1], s2 = csr_src[e + 2], s3 = csr_src[e + 3];
            float w0 = dis[s0], w1 = dis[s1], w2 = dis[s2], w3 = dis[s3];
            unsigned a = *(const unsigned*)&HW[((size_t)s0 << HBITS) + (lane << 1)];
            unsigned b = *(const unsigned*)&HW[((size_t)s1 << HBITS) + (lane << 1)];
            unsigned c = *(const unsigned*)&HW[((size_t)s2 << HBITS) + (lane << 1)];
            unsigned d = *(const unsigned*)&HW[((size_t)s3 << HBITS) + (lane << 1)];
            accx += bf2f((unsigned short)(a & 0xFFFFu)) * w0;
            accy += bf2f((unsigned short)(a >> 16)) * w0;
            accx += bf2f((unsigned short)(b & 0xFFFFu)) * w1;
            accy += bf2f((unsigned short)(b >> 16)) * w1;
            accx += bf2f((unsigned short)(c & 0xFFFFu)) * w2;
            accy += bf2f((unsigned short)(c >> 16)) * w2;
            accx += bf2f((unsigned short)(d & 0xFFFFu)) * w3;
            accy += bf2f((unsigned short)(d >> 16)) * w3;
        }
        for (; e < stop; ++e) {
            int s = csr_src[e];
            float w = dis[s];
            unsigned a = *(const unsigned*)&HW[((size_t)s << HBITS) + (lane << 1)];
            accx += bf2f((unsigned short)(a & 0xFFFFu)) * w;
            accy += bf2f((unsigned short)(a >> 16)) * w;
        }
    }
    if (half == 1) {
        float2 p; p.x = accx; p.y = accy;
        part[slot][lane] = p;
    }
    __syncthreads();
    if (valid && half == 0) {
        float2 p = part[slot][lane];
        float dd = dis[node];
        unsigned v0 = *(const unsigned*)&HW[((size_t)node << HBITS) + (lane << 1)];
        float2 b2 = *(const float2*)&bias[lane << 1];
        accx += p.x + bf2f((unsigned short)(v0 & 0xFFFFu)) * dd;
        accy += p.y + bf2f((unsigned short)(v0 >> 16)) * dd;
        accx = accx * dd + b2.x;
        accy = accy * dd + b2.y;
        unsigned o = ((unsigned)(unsigned short)f2bf(accy) << 16) | (unsigned short)f2bf(accx);
        *(unsigned*)&out[((size_t)node << HBITS) + (lane << 1)] = o;
    }
}

// ---------------------------------------------------------------------------
// Output head (bf16 h input)
// ---------------------------------------------------------------------------
#define OUT_DIM 5
__global__ void out_softmax_k(const unsigned short* __restrict__ h,
                              const float* __restrict__ Wo,
                              const float* __restrict__ bo, float* __restrict__ out, int N) {
    int gtid = blockIdx.x * blockDim.x + threadIdx.x;
    int node = gtid >> 6;
    int lane = threadIdx.x & 63;
    if (node >= N) return;
    const unsigned short* hr = h + ((size_t)node << HBITS);
    float h0 = bf2f(hr[lane]);
    float h1 = bf2f(hr[lane + 64]);
    float acc[OUT_DIM];
#pragma unroll
    for (int o = 0; o < OUT_DIM; ++o)
        acc[o] = h0 * Wo[lane * OUT_DIM + o] + h1 * Wo[(lane + 64) * OUT_DIM + o];
#pragma unroll
    for (int off = 32; off >= 1; off >>= 1) {
#pragma unroll
        for (int o = 0; o < OUT_DIM; ++o) acc[o] += __shfl_down(acc[o], off, 64);
    }
    if (lane == 0) {
        float v[OUT_DIM], m = -1e30f;
#pragma unroll
        for (int o = 0; o < OUT_DIM; ++o) { v[o] = acc[o] + bo[o]; m = fmaxf(m, v[o]); }
        float s = 0.0f;
#pragma unroll
        for (int o = 0; o < OUT_DIM; ++o) { v[o] = __builtin_amdgcn_exp2f((v[o] - m) * LOG2E); s += v[o]; }
        float inv = 1.0f / s;
#pragma unroll
        for (int o = 0; o < OUT_DIM; ++o) out[(size_t)node * OUT_DIM + o] = v[o] * inv;
    }
}

// ---------------------------------------------------------------------------
// launch
// ---------------------------------------------------------------------------
static inline int cdiv(long long a, long long b) { return (int)((a + b - 1) / b); }
static inline char* align256(char* p) {
    return (char*)(((uintptr_t)p + 255) & ~(uintptr_t)255);
}

extern "C" void kernel_launch(void* const* d_in, const int* in_sizes, int n_in,
                              void* d_out, int out_size, void* d_ws, size_t ws_size,
                              hipStream_t stream) {
    const float* x       = (const float*)d_in[0];
    const int*   eidx    = (const int*)d_in[1];
    const float* proj_W  = (const float*)d_in[2];
    const float* proj_b  = (const float*)d_in[3];
    const float* conv1_W = (const float*)d_in[4];
    const float* conv1_b = (const float*)d_in[5];
    const float* conv2_W = (const float*)d_in[6];
    const float* conv2_b = (const float*)d_in[7];
    const float* hidden_c= (const float*)d_in[8];
    const float* gru_Wih = (const float*)d_in[9];
    const float* gru_Whh = (const float*)d_in[10];
    const float* gru_bih = (const float*)d_in[11];
    const float* gru_bhh = (const float*)d_in[12];
    const float* out_W   = (const float*)d_in[13];
    const float* out_b   = (const float*)d_in[14];
    float* out = (float*)d_out;

    const int F = 16, H = 128, G3 = 384;
    const int N = in_sizes[0] / F;
    const int E = in_sizes[1] / 2;
    const int* src = eidx;
    const int* dst = eidx + E;

    const int TPB = 256;
    const int nScanBlocks = cdiv(N, 256);

    // workspace (256B-aligned slots)
    char* wp = (char*)d_ws;
#define ALLOC(ptr_t, name, bytes) ptr_t name = (ptr_t)wp; wp = align256(wp + (bytes))
    ALLOC(int*, cnt, (size_t)N * 4);
    ALLOC(int*, rowptr, (size_t)(N + 1) * 4);
    ALLOC(int*, pos, (size_t)N * 4);
    ALLOC(int*, bsum, 256 * 4);
    ALLOC(int*, csr_src, (size_t)E * 4);
    ALLOC(float*, dis, (size_t)N * 4);
    ALLOC(short*, c1Wt, (size_t)H * H * 2);
    ALLOC(short*, c2Wt, (size_t)H * H * 2);
    ALLOC(short*, WihT, (size_t)G3 * H * 2);
    ALLOC(short*, WhhT, (size_t)G3 * H * 2);
    ALLOC(unsigned short*, h0b, (size_t)N * H * 2);
    ALLOC(unsigned short*, h1b, (size_t)N * H * 2);
    ALLOC(unsigned short*, Abuf, (size_t)N * H * 2);
    ALLOC(unsigned short*, HWb, (size_t)N * H * 2);
#undef ALLOC

    const int totNH = N * H;

    // --- weight preconversion (bf16, [n][k]) ---
    cvt_bf16_t_k<<<cdiv(H * H, TPB), TPB, 0, stream>>>(conv1_W, c1Wt, H, H);
    cvt_bf16_t_k<<<cdiv(H * H, TPB), TPB, 0, stream>>>(conv2_W, c2Wt, H, H);
    cvt_bf16_k<<<cdiv(G3 * H, TPB), TPB, 0, stream>>>(gru_Wih, WihT, G3 * H);
    cvt_bf16_k<<<cdiv(G3 * H, TPB), TPB, 0, stream>>>(gru_Whh, WhhT, G3 * H);

    // --- CSR build + normalization ---
    zero_cnt_k<<<cdiv(N, TPB), TPB, 0, stream>>>(cnt, N);
    count_k<<<cdiv(E, TPB), TPB, 0, stream>>>(dst, cnt, E);
    scan1_k<<<nScanBlocks, 256, 0, stream>>>(cnt, rowptr, bsum, N);
    scan2_k<<<1, 256, 0, stream>>>(bsum, nScanBlocks);
    scan3_k<<<nScanBlocks, 256, 0, stream>>>(rowptr, bsum, cnt, pos, dis, N, E);
    reorder_k<<<cdiv(E, TPB), TPB, 0, stream>>>(src, dst, pos, csr_src, E);

    // --- h init (bf16) ---
    h_init_k<<<cdiv(totNH, TPB), TPB, 0, stream>>>(hidden_c, h0b, totNH);

    unsigned short* hb_cur = h0b;
    unsigned short* hb_nxt = h1b;

    const int gm64 = cdiv(N, 64);
    const int gatherBlocks = cdiv(N, 2);

    // --- proj (K=16, fp32 path, bf16 out) ---
    dim3 gridP(cdiv(N, BM) * (H / BN));
    gemm_k<false, false><<<gridP, TPB, 0, stream>>>(x, proj_W, proj_b, Abuf, N, F, H);

    // --- GRU step 0 (fused) ---
    gru_fused_k<false><<<gm64, TPB, 0, stream>>>(Abuf, hb_cur, WihT, WhhT,
                                                 gru_bih, gru_bhh, hb_nxt, N);
    { unsigned short* t = hb_cur; hb_cur = hb_nxt; hb_nxt = t; }

    for (int it = 0; it < 3; ++it) {
        gemm_mfma_k<false><<<gm64, TPB, 0, stream>>>(hb_cur, c1Wt, HWb, N);
        gcn_gather_k<<<gatherBlocks, TPB, 0, stream>>>(HWb, dis, rowptr, csr_src,
                                                       conv1_b, Abuf, N);
        gemm_mfma_k<true><<<gm64, TPB, 0, stream>>>(Abuf, c2Wt, HWb, N);
        gcn_gather_k<<<gatherBlocks, TPB, 0, stream>>>(HWb, dis, rowptr, csr_src,
                                                       conv2_b, Abuf, N);
        gru_fused_k<true><<<gm64, TPB, 0, stream>>>(Abuf, hb_cur, WihT, WhhT,
                                                    gru_bih, gru_bhh, hb_nxt, N);
        { unsigned short* t = hb_cur; hb_cur = hb_nxt; hb_nxt = t; }
    }

    // --- output head ---
    out_softmax_k<<<cdiv((long long)N * 64, TPB), TPB, 0, stream>>>(hb_cur, out_W, out_b, out, N);
}

// Round 13
// 573.366 us; speedup vs baseline: 1.3883x; 1.2713x over previous
//
#include <hip/hip_runtime.h>
#include <hip/hip_bf16.h>

#define NODES_H 128
#define HBITS 7   // 128 = 1<<7

typedef __attribute__((ext_vector_type(8))) short bf16x8;
typedef __attribute__((ext_vector_type(4))) float f32x4;

static __device__ __forceinline__ short f2bf(float f) {
    union { float f; unsigned u; } v; v.f = f;
    unsigned r = v.u + 0x7FFFu + ((v.u >> 16) & 1u);  // RNE
    return (short)(r >> 16);
}
static __device__ __forceinline__ float bf2f(unsigned short u) {
    union { unsigned u; float f; } v; v.u = ((unsigned)u) << 16;
    return v.f;
}
// fast sigmoid/tanh via native v_exp_f32 (2^x) + v_rcp_f32 (~1 ulp)
#define LOG2E 1.4426950408889634f
static __device__ __forceinline__ float fast_sigmoid(float x) {
    float t = __builtin_amdgcn_exp2f(-x * LOG2E);
    return __builtin_amdgcn_rcpf(1.0f + t);
}
static __device__ __forceinline__ float fast_tanh(float x) {
    float t = __builtin_amdgcn_exp2f(x * (2.0f * LOG2E));
    return 1.0f - 2.0f * __builtin_amdgcn_rcpf(t + 1.0f);
}

// ---------------------------------------------------------------------------
// weight preconversion
// ---------------------------------------------------------------------------
__global__ void cvt_bf16_k(const float* __restrict__ in, short* __restrict__ out, int n) {
    int i = blockIdx.x * blockDim.x + threadIdx.x;
    if (i < n) out[i] = f2bf(in[i]);
}

__global__ void cvt_bf16_t_k(const float* __restrict__ in, short* __restrict__ out, int K, int N) {
    int i = blockIdx.x * blockDim.x + threadIdx.x;
    if (i >= K * N) return;
    int nn = i >> HBITS;
    int kk = i & (NODES_H - 1);
    out[i] = f2bf(in[kk * N + nn]);  // out[n][k] = in[k][n], K==128
}

// ---------------------------------------------------------------------------
// CSR build
// ---------------------------------------------------------------------------
__global__ void zero_cnt_k(int* __restrict__ cnt, int N) {
    int i = blockIdx.x * blockDim.x + threadIdx.x;
    if (i < N) cnt[i] = 0;
}

__global__ void count_k(const int* __restrict__ dst, int* __restrict__ cnt, int E) {
    int e = blockIdx.x * blockDim.x + threadIdx.x;
    if (e < E) atomicAdd(&cnt[dst[e]], 1);
}

__global__ __launch_bounds__(256) void scan1_k(const int* __restrict__ cnt,
                                               int* __restrict__ rowptr,
                                               int* __restrict__ bsum, int N) {
    __shared__ int buf[256];
    int tid = threadIdx.x;
    int i = blockIdx.x * 256 + tid;
    int v = (i < N) ? cnt[i] : 0;
    buf[tid] = v;
    __syncthreads();
#pragma unroll
    for (int off = 1; off < 256; off <<= 1) {
        int t = (tid >= off) ? buf[tid - off] : 0;
        __syncthreads();
        buf[tid] += t;
        __syncthreads();
    }
    if (i < N) rowptr[i] = buf[tid] - v;
    if (tid == 255) bsum[blockIdx.x] = buf[255];
}

__global__ __launch_bounds__(256) void scan2_k(int* __restrict__ bsum, int nb) {
    __shared__ int buf[256];
    int tid = threadIdx.x;
    int v = (tid < nb) ? bsum[tid] : 0;
    buf[tid] = v;
    __syncthreads();
#pragma unroll
    for (int off = 1; off < 256; off <<= 1) {
        int t = (tid >= off) ? buf[tid - off] : 0;
        __syncthreads();
        buf[tid] += t;
        __syncthreads();
    }
    if (tid < nb) bsum[tid] = buf[tid] - v;
}

__global__ void scan3_k(int* __restrict__ rowptr, const int* __restrict__ bsum,
                        const int* __restrict__ cnt, int* __restrict__ pos,
                        float* __restrict__ dis, int N, int E) {
    int i = blockIdx.x * blockDim.x + threadIdx.x;
    if (i < N) {
        int v = rowptr[i] + bsum[blockIdx.x];
        rowptr[i] = v;
        pos[i] = v;
        dis[i] = rsqrtf((float)(cnt[i] + 1));
    }
    if (i == 0) rowptr[N] = E;
}

__global__ void reorder_k(const int* __restrict__ src, const int* __restrict__ dst,
                          int* __restrict__ pos, int* __restrict__ csr_src, int E) {
    int e = blockIdx.x * blockDim.x + threadIdx.x;
    if (e >= E) return;
    int p = atomicAdd(&pos[dst[e]], 1);
    csr_src[p] = src[e];
}

// ---------------------------------------------------------------------------
// h init (bf16 state only)
// ---------------------------------------------------------------------------
__global__ void h_init_k(const float* __restrict__ hc, unsigned short* __restrict__ hb,
                         int total) {
    int i = blockIdx.x * blockDim.x + threadIdx.x;
    if (i < total) hb[i] = (unsigned short)f2bf(hc[i & (NODES_H - 1)]);
}

// ---------------------------------------------------------------------------
// fp32 tiled GEMM (proj: K=16), bf16 output
// ---------------------------------------------------------------------------
#define BM 64
#define BN 64
#define BK 16

template <bool WT, bool RELU_A>
__global__ __launch_bounds__(256) void gemm_k(const float* __restrict__ A,
                                              const float* __restrict__ W,
                                              const float* __restrict__ bias,
                                              unsigned short* __restrict__ C,
                                              int M, int K, int N) {
    __shared__ float As[BK][BM + 1];
    __shared__ float Ws[BK][BN + 1];

    const int gn = N / BN;
    const int bx = blockIdx.x % gn;
    const int by = blockIdx.x / gn;
    const int tid = threadIdx.x;
    const int tx = tid & 15;
    const int ty = tid >> 4;
    const int row0 = by * BM;
    const int col0 = bx * BN;

    float acc[4][4] = {};

    for (int k0 = 0; k0 < K; k0 += BK) {
#pragma unroll
        for (int i = 0; i < 4; ++i) {
            int idx = tid + i * 256;
            int r = idx >> 4, k = idx & 15;
            int gr = row0 + r;
            float v = (gr < M) ? A[(size_t)gr * K + k0 + k] : 0.0f;
            if (RELU_A) v = fmaxf(v, 0.0f);
            As[k][r] = v;
        }
#pragma unroll
        for (int i = 0; i < 4; ++i) {
            int idx = tid + i * 256;
            if (!WT) {
                int k = idx >> 6, n = idx & 63;
                Ws[k][n] = W[(size_t)(k0 + k) * N + col0 + n];
            } else {
                int n = idx >> 4, k = idx & 15;
                Ws[k][n] = W[(size_t)(col0 + n) * K + k0 + k];
            }
        }
        __syncthreads();

#pragma unroll
        for (int kk = 0; kk < BK; ++kk) {
            float a[4], w[4];
#pragma unroll
            for (int i = 0; i < 4; ++i) a[i] = As[kk][ty * 4 + i];
#pragma unroll
            for (int j = 0; j < 4; ++j) w[j] = Ws[kk][tx * 4 + j];
#pragma unroll
            for (int i = 0; i < 4; ++i)
#pragma unroll
                for (int j = 0; j < 4; ++j) acc[i][j] += a[i] * w[j];
        }
        __syncthreads();
    }

#pragma unroll
    for (int i = 0; i < 4; ++i) {
        int gr = row0 + ty * 4 + i;
        if (gr >= M) continue;
#pragma unroll
        for (int j = 0; j < 4; ++j) {
            int gc = col0 + tx * 4 + j;
            float v = acc[i][j];
            if (bias) v += bias[gc];
            C[(size_t)gr * N + gc] = (unsigned short)f2bf(v);
        }
    }
}

// ---------------------------------------------------------------------------
// MFMA helpers, 64-row tile, wave split m4 x n2 (wave owns 32 cols, all rows).
// ---------------------------------------------------------------------------
struct BFrags { bf16x8 b[2][4]; };  // [n][ks]

static __device__ __forceinline__ void load_b(const short* __restrict__ Wg,
                                              int c0, int lrow, int lk, BFrags& f) {
#pragma unroll
    for (int n = 0; n < 2; ++n) {
        int cc = c0 + (n << 4) + lrow;
#pragma unroll
        for (int ks = 0; ks < 4; ++ks) {
            int chunk = (ks << 2) + lk;
            f.b[n][ks] = *(const bf16x8*)&Wg[((size_t)cc << 7) + (chunk << 3)];
        }
    }
}

static __device__ __forceinline__ void mfma_apply(const short* __restrict__ S,
                                                  const BFrags& f, int lrow, int lk,
                                                  f32x4 acc[4][2]) {
#pragma unroll
    for (int ks = 0; ks < 4; ++ks) {
        int chunk = (ks << 2) + lk;
        bf16x8 a[4];
#pragma unroll
        for (int m = 0; m < 4; ++m) {
            int rr = (m << 4) + lrow;
            a[m] = *(const bf16x8*)&S[rr * 128 + ((chunk ^ (rr & 7)) << 3)];
        }
#pragma unroll
        for (int m = 0; m < 4; ++m)
#pragma unroll
            for (int n = 0; n < 2; ++n)
                acc[m][n] = __builtin_amdgcn_mfma_f32_16x16x32_bf16(a[m], f.b[n][ks], acc[m][n], 0, 0, 0);
    }
}

// swizzled LDS read of one bf16 element (for epilogue h reuse)
static __device__ __forceinline__ float lds_bf16(const short* __restrict__ S, int r, int c) {
    return bf2f((unsigned short)S[r * 128 + (((c >> 3) ^ (r & 7)) << 3) + (c & 7)]);
}

// ---------------------------------------------------------------------------
// bf16 MFMA GEMM (convs): C = relu?(A) @ Wt^T, bf16 out. K=N=128, 64-row tile.
// (R8 known-best form)
// ---------------------------------------------------------------------------
template <bool RELU_A>
__global__ __launch_bounds__(256, 4) void gemm_mfma_k(const unsigned short* __restrict__ A,
                                                      const short* __restrict__ Wt,
                                                      unsigned short* __restrict__ C,
                                                      int M) {
    __shared__ short As[64 * 128];

    const int row0 = blockIdx.x << 6;
    const int tid = threadIdx.x;

#pragma unroll
    for (int i = 0; i < 4; ++i) {
        int chunk = tid + (i << 8);
        int r = chunk >> 4, c = chunk & 15;
        int gr = row0 + r;
        bf16x8 t;
        if (gr < M) {
            t = *(const bf16x8*)(A + (((size_t)gr) << 7) + (c << 3));
            if (RELU_A) {
#pragma unroll
                for (int j = 0; j < 8; ++j) {
                    unsigned short u = (unsigned short)t[j];
                    t[j] = (short)((u & 0x8000u) ? 0 : u);
                }
            }
        } else {
#pragma unroll
            for (int j = 0; j < 8; ++j) t[j] = 0;
        }
        *(bf16x8*)&As[r * 128 + ((c ^ (r & 7)) << 3)] = t;
    }

    const int lane = tid & 63;
    const int wid = tid >> 6;
    const int c0 = wid << 5;
    const int lrow = lane & 15;
    const int lk = lane >> 4;

    BFrags bf;
    load_b(Wt, c0, lrow, lk, bf);  // overlap with staging
    __syncthreads();

    f32x4 acc[4][2] = {};
    mfma_apply(As, bf, lrow, lk, acc);

#pragma unroll
    for (int m = 0; m < 4; ++m) {
#pragma unroll
        for (int j = 0; j < 4; ++j) {
            int gr = row0 + (m << 4) + (lk << 2) + j;
            if (gr >= M) continue;
#pragma unroll
            for (int n = 0; n < 2; ++n) {
                int gc = c0 + (n << 4) + lrow;
                C[((size_t)gr << 7) + gc] = (unsigned short)f2bf(acc[m][n][j]);
            }
        }
    }
}

// ---------------------------------------------------------------------------
// Fused GRU (64-row tile, m4 x n2): six gate GEMM passes, B DOUBLE-BUFFERED
// in registers (each load issued one full pass ahead), launch_bounds (256,2)
// so the ~180-VGPR peak does NOT spill (R10's failure mode), fast gate math,
// direct stores.
// ---------------------------------------------------------------------------
template <bool RELU_A>
__global__ __launch_bounds__(256, 2) void gru_fused_k(const unsigned short* __restrict__ A,
                                                      const unsigned short* __restrict__ hb,
                                                      const short* __restrict__ WihT,
                                                      const short* __restrict__ WhhT,
                                                      const float* __restrict__ bih,
                                                      const float* __restrict__ bhh,
                                                      unsigned short* __restrict__ hnb,
                                                      int M) {
    __shared__ short As[64 * 128];
    __shared__ short Hs[64 * 128];

    const int row0 = blockIdx.x << 6;
    const int tid = threadIdx.x;

    // stage A (relu optional) and h tiles
#pragma unroll
    for (int i = 0; i < 4; ++i) {
        int chunk = tid + (i << 8);
        int r = chunk >> 4, c = chunk & 15;
        int gr = row0 + r;
        bf16x8 ta, th;
        if (gr < M) {
            ta = *(const bf16x8*)(A + (((size_t)gr) << 7) + (c << 3));
            if (RELU_A) {
#pragma unroll
                for (int j = 0; j < 8; ++j) {
                    unsigned short u = (unsigned short)ta[j];
                    ta[j] = (short)((u & 0x8000u) ? 0 : u);
                }
            }
            th = *(const bf16x8*)(hb + (((size_t)gr) << 7) + (c << 3));
        } else {
#pragma unroll
            for (int j = 0; j < 8; ++j) { ta[j] = 0; th[j] = 0; }
        }
        int sw = r * 128 + ((c ^ (r & 7)) << 3);
        *(bf16x8*)&As[sw] = ta;
        *(bf16x8*)&Hs[sw] = th;
    }

    const int lane = tid & 63;
    const int wid = tid >> 6;
    const int c0 = wid << 5;
    const int lrow = lane & 15;
    const int lk = lane >> 4;

    // biases for this lane's columns
    float br[2], bz[2], bni[2], bnh[2];
#pragma unroll
    for (int n = 0; n < 2; ++n) {
        int gc = c0 + (n << 4) + lrow;
        br[n] = bih[gc] + bhh[gc];
        bz[n] = bih[128 + gc] + bhh[128 + gc];
        bni[n] = bih[256 + gc];
        bnh[n] = bhh[256 + gc];
    }

    const int GS = 128 * 128;  // per-gate weight stride
    BFrags bfA, bfB;
    load_b(WihT, c0, lrow, lk, bfA);           // pass 1 B (overlaps staging)
    load_b(WhhT, c0, lrow, lk, bfB);           // pass 2 B (overlaps staging)
    __syncthreads();

    f32x4 accR[4][2] = {};
    f32x4 accT[4][2] = {};

    mfma_apply(As, bfA, lrow, lk, accR);       // gi_r
    load_b(WhhT + 2 * GS, c0, lrow, lk, bfA);  // prefetch pass 3 (gh_n)
    mfma_apply(Hs, bfB, lrow, lk, accR);       // + gh_r
    load_b(WihT + 2 * GS, c0, lrow, lk, bfB);  // prefetch pass 4 (gi_n)
    mfma_apply(Hs, bfA, lrow, lk, accT);       // gh_n
    load_b(WihT + GS, c0, lrow, lk, bfA);      // prefetch pass 5 (gi_z)

    // fold: accT = r * (gh_n + bnh)   [accR dead after this]
#pragma unroll
    for (int m = 0; m < 4; ++m)
#pragma unroll
        for (int n = 0; n < 2; ++n)
#pragma unroll
            for (int j = 0; j < 4; ++j) {
                float rr = fast_sigmoid(accR[m][n][j] + br[n]);
                accT[m][n][j] = rr * (accT[m][n][j] + bnh[n]);
            }

    mfma_apply(As, bfB, lrow, lk, accT);       // += gi_n
    load_b(WhhT + GS, c0, lrow, lk, bfB);      // prefetch pass 6 (gh_z)

    // n = tanh(accT + bni)
#pragma unroll
    for (int m = 0; m < 4; ++m)
#pragma unroll
        for (int n = 0; n < 2; ++n)
#pragma unroll
            for (int j = 0; j < 4; ++j)
                accT[m][n][j] = fast_tanh(accT[m][n][j] + bni[n]);

    f32x4 accZ[4][2] = {};
    mfma_apply(As, bfA, lrow, lk, accZ);       // gi_z
    mfma_apply(Hs, bfB, lrow, lk, accZ);       // + gh_z

    // epilogue: z, h' = (1-z)*n + z*h ; h read from staged LDS tile
#pragma unroll
    for (int m = 0; m < 4; ++m) {
#pragma unroll
        for (int j = 0; j < 4; ++j) {
            int lr = (m << 4) + (lk << 2) + j;
            int grow = row0 + lr;
            if (grow >= M) continue;
#pragma unroll
            for (int n = 0; n < 2; ++n) {
                int gcol = c0 + (n << 4) + lrow;
                float zz = fast_sigmoid(accZ[m][n][j] + bz[n]);
                float hv = lds_bf16(Hs, lr, gcol);
                float v = (1.0f - zz) * accT[m][n][j] + zz * hv;
                hnb[((size_t)grow << 7) + gcol] = (unsigned short)f2bf(v);
            }
        }
    }
}

// ---------------------------------------------------------------------------
// GCN gather (pull): one wave per destination node, bf16 HW rows, 4-edge unroll
// (R8 known-best form)
// ---------------------------------------------------------------------------
__global__ __launch_bounds__(256) void gcn_gather_k(const unsigned short* __restrict__ HW,
                                                    const float* __restrict__ dis,
                                                    const int* __restrict__ rowptr,
                                                    const int* __restrict__ csr_src,
                                                    const float* __restrict__ bias,
                                                    unsigned short* __restrict__ out, int N) {
    int node = (blockIdx.x * 256 + threadIdx.x) >> 6;
    int lane = threadIdx.x & 63;
    if (node >= N) return;
    float dd = dis[node];
    unsigned v0 = *(const unsigned*)&HW[((size_t)node << HBITS) + (lane << 1)];
    float2 b2 = *(const float2*)&bias[lane << 1];
    float accx = bf2f((unsigned short)(v0 & 0xFFFFu)) * dd;
    float accy = bf2f((unsigned short)(v0 >> 16)) * dd;
    int e = rowptr[node], end = rowptr[node + 1];
    for (; e + 3 < end; e += 4) {
        int s0 = csr_src[e], s1 = csr_src[e + 1], s2 = csr_src[e + 2], s3 = csr_src[e + 3];
        float w0 = dis[s0], w1 = dis[s1], w2 = dis[s2], w3 = dis[s3];
        unsigned a = *(const unsigned*)&HW[((size_t)s0 << HBITS) + (lane << 1)];
        unsigned b = *(const unsigned*)&HW[((size_t)s1 << HBITS) + (lane << 1)];
        unsigned c = *(const unsigned*)&HW[((size_t)s2 << HBITS) + (lane << 1)];
        unsigned d = *(const unsigned*)&HW[((size_t)s3 << HBITS) + (lane << 1)];
        accx += bf2f((unsigned short)(a & 0xFFFFu)) * w0;
        accy += bf2f((unsigned short)(a >> 16)) * w0;
        accx += bf2f((unsigned short)(b & 0xFFFFu)) * w1;
        accy += bf2f((unsigned short)(b >> 16)) * w1;
        accx += bf2f((unsigned short)(c & 0xFFFFu)) * w2;
        accy += bf2f((unsigned short)(c >> 16)) * w2;
        accx += bf2f((unsigned short)(d & 0xFFFFu)) * w3;
        accy += bf2f((unsigned short)(d >> 16)) * w3;
    }
    for (; e < end; ++e) {
        int s = csr_src[e];
        float w = dis[s];
        unsigned a = *(const unsigned*)&HW[((size_t)s << HBITS) + (lane << 1)];
        accx += bf2f((unsigned short)(a & 0xFFFFu)) * w;
        accy += bf2f((unsigned short)(a >> 16)) * w;
    }
    accx = accx * dd + b2.x;
    accy = accy * dd + b2.y;
    unsigned o = ((unsigned)(unsigned short)f2bf(accy) << 16) | (unsigned short)f2bf(accx);
    *(unsigned*)&out[((size_t)node << HBITS) + (lane << 1)] = o;
}

// ---------------------------------------------------------------------------
// Output head (bf16 h input)
// ---------------------------------------------------------------------------
#define OUT_DIM 5
__global__ void out_softmax_k(const unsigned short* __restrict__ h,
                              const float* __restrict__ Wo,
                              const float* __restrict__ bo, float* __restrict__ out, int N) {
    int gtid = blockIdx.x * blockDim.x + threadIdx.x;
    int node = gtid >> 6;
    int lane = threadIdx.x & 63;
    if (node >= N) return;
    const unsigned short* hr = h + ((size_t)node << HBITS);
    float h0 = bf2f(hr[lane]);
    float h1 = bf2f(hr[lane + 64]);
    float acc[OUT_DIM];
#pragma unroll
    for (int o = 0; o < OUT_DIM; ++o)
        acc[o] = h0 * Wo[lane * OUT_DIM + o] + h1 * Wo[(lane + 64) * OUT_DIM + o];
#pragma unroll
    for (int off = 32; off >= 1; off >>= 1) {
#pragma unroll
        for (int o = 0; o < OUT_DIM; ++o) acc[o] += __shfl_down(acc[o], off, 64);
    }
    if (lane == 0) {
        float v[OUT_DIM], m = -1e30f;
#pragma unroll
        for (int o = 0; o < OUT_DIM; ++o) { v[o] = acc[o] + bo[o]; m = fmaxf(m, v[o]); }
        float s = 0.0f;
#pragma unroll
        for (int o = 0; o < OUT_DIM; ++o) { v[o] = __builtin_amdgcn_exp2f((v[o] - m) * LOG2E); s += v[o]; }
        float inv = 1.0f / s;
#pragma unroll
        for (int o = 0; o < OUT_DIM; ++o) out[(size_t)node * OUT_DIM + o] = v[o] * inv;
    }
}

// ---------------------------------------------------------------------------
// launch
// ---------------------------------------------------------------------------
static inline int cdiv(long long a, long long b) { return (int)((a + b - 1) / b); }
static inline char* align256(char* p) {
    return (char*)(((uintptr_t)p + 255) & ~(uintptr_t)255);
}

extern "C" void kernel_launch(void* const* d_in, const int* in_sizes, int n_in,
                              void* d_out, int out_size, void* d_ws, size_t ws_size,
                              hipStream_t stream) {
    const float* x       = (const float*)d_in[0];
    const int*   eidx    = (const int*)d_in[1];
    const float* proj_W  = (const float*)d_in[2];
    const float* proj_b  = (const float*)d_in[3];
    const float* conv1_W = (const float*)d_in[4];
    const float* conv1_b = (const float*)d_in[5];
    const float* conv2_W = (const float*)d_in[6];
    const float* conv2_b = (const float*)d_in[7];
    const float* hidden_c= (const float*)d_in[8];
    const float* gru_Wih = (const float*)d_in[9];
    const float* gru_Whh = (const float*)d_in[10];
    const float* gru_bih = (const float*)d_in[11];
    const float* gru_bhh = (const float*)d_in[12];
    const float* out_W   = (const float*)d_in[13];
    const float* out_b   = (const float*)d_in[14];
    float* out = (float*)d_out;

    const int F = 16, H = 128, G3 = 384;
    const int N = in_sizes[0] / F;
    const int E = in_sizes[1] / 2;
    const int* src = eidx;
    const int* dst = eidx + E;

    const int TPB = 256;
    const int nScanBlocks = cdiv(N, 256);

    // workspace (256B-aligned slots)
    char* wp = (char*)d_ws;
#define ALLOC(ptr_t, name, bytes) ptr_t name = (ptr_t)wp; wp = align256(wp + (bytes))
    ALLOC(int*, cnt, (size_t)N * 4);
    ALLOC(int*, rowptr, (size_t)(N + 1) * 4);
    ALLOC(int*, pos, (size_t)N * 4);
    ALLOC(int*, bsum, 256 * 4);
    ALLOC(int*, csr_src, (size_t)E * 4);
    ALLOC(float*, dis, (size_t)N * 4);
    ALLOC(short*, c1Wt, (size_t)H * H * 2);
    ALLOC(short*, c2Wt, (size_t)H * H * 2);
    ALLOC(short*, WihT, (size_t)G3 * H * 2);
    ALLOC(short*, WhhT, (size_t)G3 * H * 2);
    ALLOC(unsigned short*, h0b, (size_t)N * H * 2);
    ALLOC(unsigned short*, h1b, (size_t)N * H * 2);
    ALLOC(unsigned short*, Abuf, (size_t)N * H * 2);
    ALLOC(unsigned short*, HWb, (size_t)N * H * 2);
#undef ALLOC

    const int totNH = N * H;

    // --- weight preconversion (bf16, [n][k]) ---
    cvt_bf16_t_k<<<cdiv(H * H, TPB), TPB, 0, stream>>>(conv1_W, c1Wt, H, H);
    cvt_bf16_t_k<<<cdiv(H * H, TPB), TPB, 0, stream>>>(conv2_W, c2Wt, H, H);
    cvt_bf16_k<<<cdiv(G3 * H, TPB), TPB, 0, stream>>>(gru_Wih, WihT, G3 * H);
    cvt_bf16_k<<<cdiv(G3 * H, TPB), TPB, 0, stream>>>(gru_Whh, WhhT, G3 * H);

    // --- CSR build + normalization ---
    zero_cnt_k<<<cdiv(N, TPB), TPB, 0, stream>>>(cnt, N);
    count_k<<<cdiv(E, TPB), TPB, 0, stream>>>(dst, cnt, E);
    scan1_k<<<nScanBlocks, 256, 0, stream>>>(cnt, rowptr, bsum, N);
    scan2_k<<<1, 256, 0, stream>>>(bsum, nScanBlocks);
    scan3_k<<<nScanBlocks, 256, 0, stream>>>(rowptr, bsum, cnt, pos, dis, N, E);
    reorder_k<<<cdiv(E, TPB), TPB, 0, stream>>>(src, dst, pos, csr_src, E);

    // --- h init (bf16) ---
    h_init_k<<<cdiv(totNH, TPB), TPB, 0, stream>>>(hidden_c, h0b, totNH);

    unsigned short* hb_cur = h0b;
    unsigned short* hb_nxt = h1b;

    const int gm64 = cdiv(N, 64);
    const int gatherBlocks = cdiv((long long)N * 64, TPB);

    // --- proj (K=16, fp32 path, bf16 out) ---
    dim3 gridP(cdiv(N, BM) * (H / BN));
    gemm_k<false, false><<<gridP, TPB, 0, stream>>>(x, proj_W, proj_b, Abuf, N, F, H);

    // --- GRU step 0 (fused) ---
    gru_fused_k<false><<<gm64, TPB, 0, stream>>>(Abuf, hb_cur, WihT, WhhT,
                                                 gru_bih, gru_bhh, hb_nxt, N);
    { unsigned short* t = hb_cur; hb_cur = hb_nxt; hb_nxt = t; }

    for (int it = 0; it < 3; ++it) {
        gemm_mfma_k<false><<<gm64, TPB, 0, stream>>>(hb_cur, c1Wt, HWb, N);
        gcn_gather_k<<<gatherBlocks, TPB, 0, stream>>>(HWb, dis, rowptr, csr_src,
                                                       conv1_b, Abuf, N);
        gemm_mfma_k<true><<<gm64, TPB, 0, stream>>>(Abuf, c2Wt, HWb, N);
        gcn_gather_k<<<gatherBlocks, TPB, 0, stream>>>(HWb, dis, rowptr, csr_src,
                                                       conv2_b, Abuf, N);
        gru_fused_k<true><<<gm64, TPB, 0, stream>>>(Abuf, hb_cur, WihT, WhhT,
                                                    gru_bih, gru_bhh, hb_nxt, N);
        { unsigned short* t = hb_cur; hb_cur = hb_nxt; hb_nxt = t; }
    }

    // --- output head ---
    out_softmax_k<<<cdiv((long long)N * 64, TPB), TPB, 0, stream>>>(hb_cur, out_W, out_b, out, N);
}

// Round 14
// 558.699 us; speedup vs baseline: 1.4248x; 1.0263x over previous
//
#include <hip/hip_runtime.h>
#include <hip/hip_bf16.h>

#define NODES_H 128
#define HBITS 7   // 128 = 1<<7

typedef __attribute__((ext_vector_type(8))) short bf16x8;
typedef __attribute__((ext_vector_type(4))) float f32x4;

static __device__ __forceinline__ short f2bf(float f) {
    union { float f; unsigned u; } v; v.f = f;
    unsigned r = v.u + 0x7FFFu + ((v.u >> 16) & 1u);  // RNE
    return (short)(r >> 16);
}
static __device__ __forceinline__ float bf2f(unsigned short u) {
    union { unsigned u; float f; } v; v.u = ((unsigned)u) << 16;
    return v.f;
}
// fast sigmoid/tanh via native v_exp_f32 (2^x) + v_rcp_f32 (~1 ulp)
#define LOG2E 1.4426950408889634f
static __device__ __forceinline__ float fast_sigmoid(float x) {
    float t = __builtin_amdgcn_exp2f(-x * LOG2E);
    return __builtin_amdgcn_rcpf(1.0f + t);
}
static __device__ __forceinline__ float fast_tanh(float x) {
    float t = __builtin_amdgcn_exp2f(x * (2.0f * LOG2E));
    return 1.0f - 2.0f * __builtin_amdgcn_rcpf(t + 1.0f);
}

// ---------------------------------------------------------------------------
// weight preconversion
// ---------------------------------------------------------------------------
__global__ void cvt_bf16_k(const float* __restrict__ in, short* __restrict__ out, int n) {
    int i = blockIdx.x * blockDim.x + threadIdx.x;
    if (i < n) out[i] = f2bf(in[i]);
}

__global__ void cvt_bf16_t_k(const float* __restrict__ in, short* __restrict__ out, int K, int N) {
    int i = blockIdx.x * blockDim.x + threadIdx.x;
    if (i >= K * N) return;
    int nn = i >> HBITS;
    int kk = i & (NODES_H - 1);
    out[i] = f2bf(in[kk * N + nn]);  // out[n][k] = in[k][n], K==128
}

// ---------------------------------------------------------------------------
// CSR build: node histogram -> scan -> bucketed two-stage reorder
// ---------------------------------------------------------------------------
__global__ void zero_cnt_k(int* __restrict__ cnt, int N) {
    int i = blockIdx.x * blockDim.x + threadIdx.x;
    if (i < N) cnt[i] = 0;
}

__global__ void count_k(const int* __restrict__ dst, int* __restrict__ cnt, int E) {
    int e = blockIdx.x * blockDim.x + threadIdx.x;
    if (e < E) atomicAdd(&cnt[dst[e]], 1);
}

__global__ __launch_bounds__(256) void scan1_k(const int* __restrict__ cnt,
                                               int* __restrict__ rowptr,
                                               int* __restrict__ bsum, int N) {
    __shared__ int buf[256];
    int tid = threadIdx.x;
    int i = blockIdx.x * 256 + tid;
    int v = (i < N) ? cnt[i] : 0;
    buf[tid] = v;
    __syncthreads();
#pragma unroll
    for (int off = 1; off < 256; off <<= 1) {
        int t = (tid >= off) ? buf[tid - off] : 0;
        __syncthreads();
        buf[tid] += t;
        __syncthreads();
    }
    if (i < N) rowptr[i] = buf[tid] - v;
    if (tid == 255) bsum[blockIdx.x] = buf[255];
}

__global__ __launch_bounds__(256) void scan2_k(int* __restrict__ bsum, int nb) {
    __shared__ int buf[256];
    int tid = threadIdx.x;
    int v = (tid < nb) ? bsum[tid] : 0;
    buf[tid] = v;
    __syncthreads();
#pragma unroll
    for (int off = 1; off < 256; off <<= 1) {
        int t = (tid >= off) ? buf[tid - off] : 0;
        __syncthreads();
        buf[tid] += t;
        __syncthreads();
    }
    if (tid < nb) bsum[tid] = buf[tid] - v;
}

// finalize node-level rowptr (+ dis)
__global__ void scan3_k(int* __restrict__ rowptr, const int* __restrict__ bsum,
                        const int* __restrict__ cnt, float* __restrict__ dis,
                        int N, int E) {
    int i = blockIdx.x * blockDim.x + threadIdx.x;
    if (i < N) {
        rowptr[i] += bsum[blockIdx.x];
        dis[i] = rsqrtf((float)(cnt[i] + 1));
    }
    if (i == 0) rowptr[N] = E;
}

// generic scan finalize: data[i] += bsum[i/256]
__global__ void scanfin_k(int* __restrict__ data, const int* __restrict__ bsum, int n) {
    int i = blockIdx.x * blockDim.x + threadIdx.x;
    if (i < n) data[i] += bsum[i >> 8];
}

// Stage A: per-chunk bucket histogram. 256 chunks x 256 buckets (bucket = dst>>8).
// fcnt layout bucket-major: fcnt[b*256 + c].
__global__ __launch_bounds__(256) void binA_k(const int* __restrict__ dst,
                                              int* __restrict__ fcnt, int E, int CH) {
    __shared__ int lcnt[256];
    const int c = blockIdx.x, tid = threadIdx.x;
    lcnt[tid] = 0;
    __syncthreads();
    int base = c * CH, stop = min(E, base + CH);
    for (int e = base + tid; e < stop; e += 256)
        atomicAdd(&lcnt[dst[e] >> 8], 1);
    __syncthreads();
    fcnt[tid * 256 + c] = lcnt[tid];
}

// Stage B: scatter packed edges into bucket/chunk-ordered ubuf.
// ubuf entry: ((dst & 255) << 16) | src   (both < 65536)
__global__ __launch_bounds__(256) void binB_k(const int* __restrict__ src,
                                              const int* __restrict__ dst,
                                              const int* __restrict__ foff,
                                              unsigned* __restrict__ ubuf, int E, int CH) {
    __shared__ int cur[256];
    const int c = blockIdx.x, tid = threadIdx.x;
    cur[tid] = foff[tid * 256 + c];
    __syncthreads();
    int base = c * CH, stop = min(E, base + CH);
    for (int e = base + tid; e < stop; e += 256) {
        int d = dst[e];
        int p = atomicAdd(&cur[d >> 8], 1);
        ubuf[p] = (((unsigned)(d & 255)) << 16) | (unsigned)src[e];
    }
}

// Stage C: per-bucket final CSR placement (contiguous ubuf read, LDS cursors,
// writes confined to the bucket's contiguous csr range -> single-L2 locality).
__global__ __launch_bounds__(256) void binC_k(const unsigned* __restrict__ ubuf,
                                              const int* __restrict__ foff,
                                              const int* __restrict__ rowptr,
                                              int* __restrict__ csr_src, int N, int E) {
    __shared__ int cur[256];
    const int b = blockIdx.x, tid = threadIdx.x;
    const int node0 = b << 8;
    if (node0 + tid < N) cur[tid] = rowptr[node0 + tid];
    __syncthreads();
    int beg = foff[b << 8];
    int end = (b < 255) ? foff[(b + 1) << 8] : E;
    for (int e = beg + tid; e < end; e += 256) {
        unsigned u = ubuf[e];
        int lnode = (int)(u >> 16);
        int p = atomicAdd(&cur[lnode], 1);
        csr_src[p] = (int)(u & 0xFFFFu);
    }
}

// ---------------------------------------------------------------------------
// h init (bf16 state only)
// ---------------------------------------------------------------------------
__global__ void h_init_k(const float* __restrict__ hc, unsigned short* __restrict__ hb,
                         int total) {
    int i = blockIdx.x * blockDim.x + threadIdx.x;
    if (i < total) hb[i] = (unsigned short)f2bf(hc[i & (NODES_H - 1)]);
}

// ---------------------------------------------------------------------------
// fp32 tiled GEMM (proj: K=16), bf16 output
// ---------------------------------------------------------------------------
#define BM 64
#define BN 64
#define BK 16

template <bool WT, bool RELU_A>
__global__ __launch_bounds__(256) void gemm_k(const float* __restrict__ A,
                                              const float* __restrict__ W,
                                              const float* __restrict__ bias,
                                              unsigned short* __restrict__ C,
                                              int M, int K, int N) {
    __shared__ float As[BK][BM + 1];
    __shared__ float Ws[BK][BN + 1];

    const int gn = N / BN;
    const int bx = blockIdx.x % gn;
    const int by = blockIdx.x / gn;
    const int tid = threadIdx.x;
    const int tx = tid & 15;
    const int ty = tid >> 4;
    const int row0 = by * BM;
    const int col0 = bx * BN;

    float acc[4][4] = {};

    for (int k0 = 0; k0 < K; k0 += BK) {
#pragma unroll
        for (int i = 0; i < 4; ++i) {
            int idx = tid + i * 256;
            int r = idx >> 4, k = idx & 15;
            int gr = row0 + r;
            float v = (gr < M) ? A[(size_t)gr * K + k0 + k] : 0.0f;
            if (RELU_A) v = fmaxf(v, 0.0f);
            As[k][r] = v;
        }
#pragma unroll
        for (int i = 0; i < 4; ++i) {
            int idx = tid + i * 256;
            if (!WT) {
                int k = idx >> 6, n = idx & 63;
                Ws[k][n] = W[(size_t)(k0 + k) * N + col0 + n];
            } else {
                int n = idx >> 4, k = idx & 15;
                Ws[k][n] = W[(size_t)(col0 + n) * K + k0 + k];
            }
        }
        __syncthreads();

#pragma unroll
        for (int kk = 0; kk < BK; ++kk) {
            float a[4], w[4];
#pragma unroll
            for (int i = 0; i < 4; ++i) a[i] = As[kk][ty * 4 + i];
#pragma unroll
            for (int j = 0; j < 4; ++j) w[j] = Ws[kk][tx * 4 + j];
#pragma unroll
            for (int i = 0; i < 4; ++i)
#pragma unroll
                for (int j = 0; j < 4; ++j) acc[i][j] += a[i] * w[j];
        }
        __syncthreads();
    }

#pragma unroll
    for (int i = 0; i < 4; ++i) {
        int gr = row0 + ty * 4 + i;
        if (gr >= M) continue;
#pragma unroll
        for (int j = 0; j < 4; ++j) {
            int gc = col0 + tx * 4 + j;
            float v = acc[i][j];
            if (bias) v += bias[gc];
            C[(size_t)gr * N + gc] = (unsigned short)f2bf(v);
        }
    }
}

// ---------------------------------------------------------------------------
// MFMA helpers, 64-row tile, wave split m4 x n2 (wave owns 32 cols, all rows).
// ---------------------------------------------------------------------------
struct BFrags { bf16x8 b[2][4]; };  // [n][ks]

static __device__ __forceinline__ void load_b(const short* __restrict__ Wg,
                                              int c0, int lrow, int lk, BFrags& f) {
#pragma unroll
    for (int n = 0; n < 2; ++n) {
        int cc = c0 + (n << 4) + lrow;
#pragma unroll
        for (int ks = 0; ks < 4; ++ks) {
            int chunk = (ks << 2) + lk;
            f.b[n][ks] = *(const bf16x8*)&Wg[((size_t)cc << 7) + (chunk << 3)];
        }
    }
}

static __device__ __forceinline__ void mfma_apply(const short* __restrict__ S,
                                                  const BFrags& f, int lrow, int lk,
                                                  f32x4 acc[4][2]) {
#pragma unroll
    for (int ks = 0; ks < 4; ++ks) {
        int chunk = (ks << 2) + lk;
        bf16x8 a[4];
#pragma unroll
        for (int m = 0; m < 4; ++m) {
            int rr = (m << 4) + lrow;
            a[m] = *(const bf16x8*)&S[rr * 128 + ((chunk ^ (rr & 7)) << 3)];
        }
#pragma unroll
        for (int m = 0; m < 4; ++m)
#pragma unroll
            for (int n = 0; n < 2; ++n)
                acc[m][n] = __builtin_amdgcn_mfma_f32_16x16x32_bf16(a[m], f.b[n][ks], acc[m][n], 0, 0, 0);
    }
}

// swizzled LDS read of one bf16 element (for epilogue h reuse)
static __device__ __forceinline__ float lds_bf16(const short* __restrict__ S, int r, int c) {
    return bf2f((unsigned short)S[r * 128 + (((c >> 3) ^ (r & 7)) << 3) + (c & 7)]);
}

// ---------------------------------------------------------------------------
// bf16 MFMA GEMM (convs): C = relu?(A) @ Wt^T, bf16 out. K=N=128, 64-row tile.
// ---------------------------------------------------------------------------
template <bool RELU_A>
__global__ __launch_bounds__(256, 4) void gemm_mfma_k(const unsigned short* __restrict__ A,
                                                      const short* __restrict__ Wt,
                                                      unsigned short* __restrict__ C,
                                                      int M) {
    __shared__ short As[64 * 128];

    const int row0 = blockIdx.x << 6;
    const int tid = threadIdx.x;

#pragma unroll
    for (int i = 0; i < 4; ++i) {
        int chunk = tid + (i << 8);
        int r = chunk >> 4, c = chunk & 15;
        int gr = row0 + r;
        bf16x8 t;
        if (gr < M) {
            t = *(const bf16x8*)(A + (((size_t)gr) << 7) + (c << 3));
            if (RELU_A) {
#pragma unroll
                for (int j = 0; j < 8; ++j) {
                    unsigned short u = (unsigned short)t[j];
                    t[j] = (short)((u & 0x8000u) ? 0 : u);
                }
            }
        } else {
#pragma unroll
            for (int j = 0; j < 8; ++j) t[j] = 0;
        }
        *(bf16x8*)&As[r * 128 + ((c ^ (r & 7)) << 3)] = t;
    }

    const int lane = tid & 63;
    const int wid = tid >> 6;
    const int c0 = wid << 5;
    const int lrow = lane & 15;
    const int lk = lane >> 4;

    BFrags bf;
    load_b(Wt, c0, lrow, lk, bf);  // overlap with staging
    __syncthreads();

    f32x4 acc[4][2] = {};
    mfma_apply(As, bf, lrow, lk, acc);

#pragma unroll
    for (int m = 0; m < 4; ++m) {
#pragma unroll
        for (int j = 0; j < 4; ++j) {
            int gr = row0 + (m << 4) + (lk << 2) + j;
            if (gr >= M) continue;
#pragma unroll
            for (int n = 0; n < 2; ++n) {
                int gc = c0 + (n << 4) + lrow;
                C[((size_t)gr << 7) + gc] = (unsigned short)f2bf(acc[m][n][j]);
            }
        }
    }
}

// ---------------------------------------------------------------------------
// Fused GRU (64-row tile, m4 x n2): six gate GEMM passes, B DOUBLE-BUFFERED
// in registers (each load issued one full pass ahead), launch_bounds (256,2)
// so the ~180-VGPR peak does NOT spill, fast gate math, direct stores.
// ---------------------------------------------------------------------------
template <bool RELU_A>
__global__ __launch_bounds__(256, 2) void gru_fused_k(const unsigned short* __restrict__ A,
                                                      const unsigned short* __restrict__ hb,
                                                      const short* __restrict__ WihT,
                                                      const short* __restrict__ WhhT,
                                                      const float* __restrict__ bih,
                                                      const float* __restrict__ bhh,
                                                      unsigned short* __restrict__ hnb,
                                                      int M) {
    __shared__ short As[64 * 128];
    __shared__ short Hs[64 * 128];

    const int row0 = blockIdx.x << 6;
    const int tid = threadIdx.x;

    // stage A (relu optional) and h tiles
#pragma unroll
    for (int i = 0; i < 4; ++i) {
        int chunk = tid + (i << 8);
        int r = chunk >> 4, c = chunk & 15;
        int gr = row0 + r;
        bf16x8 ta, th;
        if (gr < M) {
            ta = *(const bf16x8*)(A + (((size_t)gr) << 7) + (c << 3));
            if (RELU_A) {
#pragma unroll
                for (int j = 0; j < 8; ++j) {
                    unsigned short u = (unsigned short)ta[j];
                    ta[j] = (short)((u & 0x8000u) ? 0 : u);
                }
            }
            th = *(const bf16x8*)(hb + (((size_t)gr) << 7) + (c << 3));
        } else {
#pragma unroll
            for (int j = 0; j < 8; ++j) { ta[j] = 0; th[j] = 0; }
        }
        int sw = r * 128 + ((c ^ (r & 7)) << 3);
        *(bf16x8*)&As[sw] = ta;
        *(bf16x8*)&Hs[sw] = th;
    }

    const int lane = tid & 63;
    const int wid = tid >> 6;
    const int c0 = wid << 5;
    const int lrow = lane & 15;
    const int lk = lane >> 4;

    // biases for this lane's columns
    float br[2], bz[2], bni[2], bnh[2];
#pragma unroll
    for (int n = 0; n < 2; ++n) {
        int gc = c0 + (n << 4) + lrow;
        br[n] = bih[gc] + bhh[gc];
        bz[n] = bih[128 + gc] + bhh[128 + gc];
        bni[n] = bih[256 + gc];
        bnh[n] = bhh[256 + gc];
    }

    const int GS = 128 * 128;  // per-gate weight stride
    BFrags bfA, bfB;
    load_b(WihT, c0, lrow, lk, bfA);           // pass 1 B (overlaps staging)
    load_b(WhhT, c0, lrow, lk, bfB);           // pass 2 B (overlaps staging)
    __syncthreads();

    f32x4 accR[4][2] = {};
    f32x4 accT[4][2] = {};

    mfma_apply(As, bfA, lrow, lk, accR);       // gi_r
    load_b(WhhT + 2 * GS, c0, lrow, lk, bfA);  // prefetch pass 3 (gh_n)
    mfma_apply(Hs, bfB, lrow, lk, accR);       // + gh_r
    load_b(WihT + 2 * GS, c0, lrow, lk, bfB);  // prefetch pass 4 (gi_n)
    mfma_apply(Hs, bfA, lrow, lk, accT);       // gh_n
    load_b(WihT + GS, c0, lrow, lk, bfA);      // prefetch pass 5 (gi_z)

    // fold: accT = r * (gh_n + bnh)   [accR dead after this]
#pragma unroll
    for (int m = 0; m < 4; ++m)
#pragma unroll
        for (int n = 0; n < 2; ++n)
#pragma unroll
            for (int j = 0; j < 4; ++j) {
                float rr = fast_sigmoid(accR[m][n][j] + br[n]);
                accT[m][n][j] = rr * (accT[m][n][j] + bnh[n]);
            }

    mfma_apply(As, bfB, lrow, lk, accT);       // += gi_n
    load_b(WhhT + GS, c0, lrow, lk, bfB);      // prefetch pass 6 (gh_z)

    // n = tanh(accT + bni)
#pragma unroll
    for (int m = 0; m < 4; ++m)
#pragma unroll
        for (int n = 0; n < 2; ++n)
#pragma unroll
            for (int j = 0; j < 4; ++j)
                accT[m][n][j] = fast_tanh(accT[m][n][j] + bni[n]);

    f32x4 accZ[4][2] = {};
    mfma_apply(As, bfA, lrow, lk, accZ);       // gi_z
    mfma_apply(Hs, bfB, lrow, lk, accZ);       // + gh_z

    // epilogue: z, h' = (1-z)*n + z*h ; h read from staged LDS tile
#pragma unroll
    for (int m = 0; m < 4; ++m) {
#pragma unroll
        for (int j = 0; j < 4; ++j) {
            int lr = (m << 4) + (lk << 2) + j;
            int grow = row0 + lr;
            if (grow >= M) continue;
#pragma unroll
            for (int n = 0; n < 2; ++n) {
                int gcol = c0 + (n << 4) + lrow;
                float zz = fast_sigmoid(accZ[m][n][j] + bz[n]);
                float hv = lds_bf16(Hs, lr, gcol);
                float v = (1.0f - zz) * accT[m][n][j] + zz * hv;
                hnb[((size_t)grow << 7) + gcol] = (unsigned short)f2bf(v);
            }
        }
    }
}

// ---------------------------------------------------------------------------
// GCN gather (pull): one wave per destination node, bf16 HW rows, 4-edge unroll
// ---------------------------------------------------------------------------
__global__ __launch_bounds__(256) void gcn_gather_k(const unsigned short* __restrict__ HW,
                                                    const float* __restrict__ dis,
                                                    const int* __restrict__ rowptr,
                                                    const int* __restrict__ csr_src,
                                                    const float* __restrict__ bias,
                                                    unsigned short* __restrict__ out, int N) {
    int node = (blockIdx.x * 256 + threadIdx.x) >> 6;
    int lane = threadIdx.x & 63;
    if (node >= N) return;
    float dd = dis[node];
    unsigned v0 = *(const unsigned*)&HW[((size_t)node << HBITS) + (lane << 1)];
    float2 b2 = *(const float2*)&bias[lane << 1];
    float accx = bf2f((unsigned short)(v0 & 0xFFFFu)) * dd;
    float accy = bf2f((unsigned short)(v0 >> 16)) * dd;
    int e = rowptr[node], end = rowptr[node + 1];
    for (; e + 3 < end; e += 4) {
        int s0 = csr_src[e], s1 = csr_src[e + 1], s2 = csr_src[e + 2], s3 = csr_src[e + 3];
        float w0 = dis[s0], w1 = dis[s1], w2 = dis[s2], w3 = dis[s3];
        unsigned a = *(const unsigned*)&HW[((size_t)s0 << HBITS) + (lane << 1)];
        unsigned b = *(const unsigned*)&HW[((size_t)s1 << HBITS) + (lane << 1)];
        unsigned c = *(const unsigned*)&HW[((size_t)s2 << HBITS) + (lane << 1)];
        unsigned d = *(const unsigned*)&HW[((size_t)s3 << HBITS) + (lane << 1)];
        accx += bf2f((unsigned short)(a & 0xFFFFu)) * w0;
        accy += bf2f((unsigned short)(a >> 16)) * w0;
        accx += bf2f((unsigned short)(b & 0xFFFFu)) * w1;
        accy += bf2f((unsigned short)(b >> 16)) * w1;
        accx += bf2f((unsigned short)(c & 0xFFFFu)) * w2;
        accy += bf2f((unsigned short)(c >> 16)) * w2;
        accx += bf2f((unsigned short)(d & 0xFFFFu)) * w3;
        accy += bf2f((unsigned short)(d >> 16)) * w3;
    }
    for (; e < end; ++e) {
        int s = csr_src[e];
        float w = dis[s];
        unsigned a = *(const unsigned*)&HW[((size_t)s << HBITS) + (lane << 1)];
        accx += bf2f((unsigned short)(a & 0xFFFFu)) * w;
        accy += bf2f((unsigned short)(a >> 16)) * w;
    }
    accx = accx * dd + b2.x;
    accy = accy * dd + b2.y;
    unsigned o = ((unsigned)(unsigned short)f2bf(accy) << 16) | (unsigned short)f2bf(accx);
    *(unsigned*)&out[((size_t)node << HBITS) + (lane << 1)] = o;
}

// ---------------------------------------------------------------------------
// Output head (bf16 h input)
// ---------------------------------------------------------------------------
#define OUT_DIM 5
__global__ void out_softmax_k(const unsigned short* __restrict__ h,
                              const float* __restrict__ Wo,
                              const float* __restrict__ bo, float* __restrict__ out, int N) {
    int gtid = blockIdx.x * blockDim.x + threadIdx.x;
    int node = gtid >> 6;
    int lane = threadIdx.x & 63;
    if (node >= N) return;
    const unsigned short* hr = h + ((size_t)node << HBITS);
    float h0 = bf2f(hr[lane]);
    float h1 = bf2f(hr[lane + 64]);
    float acc[OUT_DIM];
#pragma unroll
    for (int o = 0; o < OUT_DIM; ++o)
        acc[o] = h0 * Wo[lane * OUT_DIM + o] + h1 * Wo[(lane + 64) * OUT_DIM + o];
#pragma unroll
    for (int off = 32; off >= 1; off >>= 1) {
#pragma unroll
        for (int o = 0; o < OUT_DIM; ++o) acc[o] += __shfl_down(acc[o], off, 64);
    }
    if (lane == 0) {
        float v[OUT_DIM], m = -1e30f;
#pragma unroll
        for (int o = 0; o < OUT_DIM; ++o) { v[o] = acc[o] + bo[o]; m = fmaxf(m, v[o]); }
        float s = 0.0f;
#pragma unroll
        for (int o = 0; o < OUT_DIM; ++o) { v[o] = __builtin_amdgcn_exp2f((v[o] - m) * LOG2E); s += v[o]; }
        float inv = 1.0f / s;
#pragma unroll
        for (int o = 0; o < OUT_DIM; ++o) out[(size_t)node * OUT_DIM + o] = v[o] * inv;
    }
}

// ---------------------------------------------------------------------------
// launch
// ---------------------------------------------------------------------------
static inline int cdiv(long long a, long long b) { return (int)((a + b - 1) / b); }
static inline char* align256(char* p) {
    return (char*)(((uintptr_t)p + 255) & ~(uintptr_t)255);
}

extern "C" void kernel_launch(void* const* d_in, const int* in_sizes, int n_in,
                              void* d_out, int out_size, void* d_ws, size_t ws_size,
                              hipStream_t stream) {
    const float* x       = (const float*)d_in[0];
    const int*   eidx    = (const int*)d_in[1];
    const float* proj_W  = (const float*)d_in[2];
    const float* proj_b  = (const float*)d_in[3];
    const float* conv1_W = (const float*)d_in[4];
    const float* conv1_b = (const float*)d_in[5];
    const float* conv2_W = (const float*)d_in[6];
    const float* conv2_b = (const float*)d_in[7];
    const float* hidden_c= (const float*)d_in[8];
    const float* gru_Wih = (const float*)d_in[9];
    const float* gru_Whh = (const float*)d_in[10];
    const float* gru_bih = (const float*)d_in[11];
    const float* gru_bhh = (const float*)d_in[12];
    const float* out_W   = (const float*)d_in[13];
    const float* out_b   = (const float*)d_in[14];
    float* out = (float*)d_out;

    const int F = 16, H = 128, G3 = 384;
    const int N = in_sizes[0] / F;
    const int E = in_sizes[1] / 2;
    const int* src = eidx;
    const int* dst = eidx + E;

    const int TPB = 256;
    const int nScanBlocks = cdiv(N, 256);
    const int CH = cdiv(E, 256);            // edges per binning chunk
    const int FLAT = 256 * 256;             // bucket-major (b,c) table size

    // workspace (256B-aligned slots)
    char* wp = (char*)d_ws;
#define ALLOC(ptr_t, name, bytes) ptr_t name = (ptr_t)wp; wp = align256(wp + (bytes))
    ALLOC(int*, cnt, (size_t)N * 4);
    ALLOC(int*, rowptr, (size_t)(N + 1) * 4);
    ALLOC(int*, bsum, 256 * 4);
    ALLOC(int*, fcnt, (size_t)FLAT * 4);
    ALLOC(int*, foff, (size_t)FLAT * 4);
    ALLOC(int*, bsum2, 256 * 4);
    ALLOC(unsigned*, ubuf, (size_t)E * 4);
    ALLOC(int*, csr_src, (size_t)E * 4);
    ALLOC(float*, dis, (size_t)N * 4);
    ALLOC(short*, c1Wt, (size_t)H * H * 2);
    ALLOC(short*, c2Wt, (size_t)H * H * 2);
    ALLOC(short*, WihT, (size_t)G3 * H * 2);
    ALLOC(short*, WhhT, (size_t)G3 * H * 2);
    ALLOC(unsigned short*, h0b, (size_t)N * H * 2);
    ALLOC(unsigned short*, h1b, (size_t)N * H * 2);
    ALLOC(unsigned short*, Abuf, (size_t)N * H * 2);
    ALLOC(unsigned short*, HWb, (size_t)N * H * 2);
#undef ALLOC

    const int totNH = N * H;

    // --- weight preconversion (bf16, [n][k]) ---
    cvt_bf16_t_k<<<cdiv(H * H, TPB), TPB, 0, stream>>>(conv1_W, c1Wt, H, H);
    cvt_bf16_t_k<<<cdiv(H * H, TPB), TPB, 0, stream>>>(conv2_W, c2Wt, H, H);
    cvt_bf16_k<<<cdiv(G3 * H, TPB), TPB, 0, stream>>>(gru_Wih, WihT, G3 * H);
    cvt_bf16_k<<<cdiv(G3 * H, TPB), TPB, 0, stream>>>(gru_Whh, WhhT, G3 * H);

    // --- node histogram + rowptr + dis ---
    zero_cnt_k<<<cdiv(N, TPB), TPB, 0, stream>>>(cnt, N);
    count_k<<<cdiv(E, TPB), TPB, 0, stream>>>(dst, cnt, E);
    scan1_k<<<nScanBlocks, 256, 0, stream>>>(cnt, rowptr, bsum, N);
    scan2_k<<<1, 256, 0, stream>>>(bsum, nScanBlocks);
    scan3_k<<<nScanBlocks, 256, 0, stream>>>(rowptr, bsum, cnt, dis, N, E);

    // --- bucketed reorder: binA -> flat scan -> binB -> binC ---
    binA_k<<<256, 256, 0, stream>>>(dst, fcnt, E, CH);
    scan1_k<<<256, 256, 0, stream>>>(fcnt, foff, bsum2, FLAT);
    scan2_k<<<1, 256, 0, stream>>>(bsum2, 256);
    scanfin_k<<<cdiv(FLAT, TPB), TPB, 0, stream>>>(foff, bsum2, FLAT);
    binB_k<<<256, 256, 0, stream>>>(src, dst, foff, ubuf, E, CH);
    binC_k<<<cdiv(N, 256), 256, 0, stream>>>(ubuf, foff, rowptr, csr_src, N, E);

    // --- h init (bf16) ---
    h_init_k<<<cdiv(totNH, TPB), TPB, 0, stream>>>(hidden_c, h0b, totNH);

    unsigned short* hb_cur = h0b;
    unsigned short* hb_nxt = h1b;

    const int gm64 = cdiv(N, 64);
    const int gatherBlocks = cdiv((long long)N * 64, TPB);

    // --- proj (K=16, fp32 path, bf16 out) ---
    dim3 gridP(cdiv(N, BM) * (H / BN));
    gemm_k<false, false><<<gridP, TPB, 0, stream>>>(x, proj_W, proj_b, Abuf, N, F, H);

    // --- GRU step 0 (fused) ---
    gru_fused_k<false><<<gm64, TPB, 0, stream>>>(Abuf, hb_cur, WihT, WhhT,
                                                 gru_bih, gru_bhh, hb_nxt, N);
    { unsigned short* t = hb_cur; hb_cur = hb_nxt; hb_nxt = t; }

    for (int it = 0; it < 3; ++it) {
        gemm_mfma_k<false><<<gm64, TPB, 0, stream>>>(hb_cur, c1Wt, HWb, N);
        gcn_gather_k<<<gatherBlocks, TPB, 0, stream>>>(HWb, dis, rowptr, csr_src,
                                                       conv1_b, Abuf, N);
        gemm_mfma_k<true><<<gm64, TPB, 0, stream>>>(Abuf, c2Wt, HWb, N);
        gcn_gather_k<<<gatherBlocks, TPB, 0, stream>>>(HWb, dis, rowptr, csr_src,
                                                       conv2_b, Abuf, N);
        gru_fused_k<true><<<gm64, TPB, 0, stream>>>(Abuf, hb_cur, WihT, WhhT,
                                                    gru_bih, gru_bhh, hb_nxt, N);
        { unsigned short* t = hb_cur; hb_cur = hb_nxt; hb_nxt = t; }
    }

    // --- output head ---
    out_softmax_k<<<cdiv((long long)N * 64, TPB), TPB, 0, stream>>>(hb_cur, out_W, out_b, out, N);
}

// Round 15
// 549.083 us; speedup vs baseline: 1.4497x; 1.0175x over previous
//
#include <hip/hip_runtime.h>
#include <hip/hip_bf16.h>

#define NODES_H 128
#define HBITS 7   // 128 = 1<<7

typedef __attribute__((ext_vector_type(8))) short bf16x8;
typedef __attribute__((ext_vector_type(4))) float f32x4;

static __device__ __forceinline__ short f2bf(float f) {
    union { float f; unsigned u; } v; v.f = f;
    unsigned r = v.u + 0x7FFFu + ((v.u >> 16) & 1u);  // RNE
    return (short)(r >> 16);
}
static __device__ __forceinline__ float bf2f(unsigned short u) {
    union { unsigned u; float f; } v; v.u = ((unsigned)u) << 16;
    return v.f;
}
// fast sigmoid/tanh via native v_exp_f32 (2^x) + v_rcp_f32 (~1 ulp)
#define LOG2E 1.4426950408889634f
static __device__ __forceinline__ float fast_sigmoid(float x) {
    float t = __builtin_amdgcn_exp2f(-x * LOG2E);
    return __builtin_amdgcn_rcpf(1.0f + t);
}
static __device__ __forceinline__ float fast_tanh(float x) {
    float t = __builtin_amdgcn_exp2f(x * (2.0f * LOG2E));
    return 1.0f - 2.0f * __builtin_amdgcn_rcpf(t + 1.0f);
}

// ---------------------------------------------------------------------------
// weight preconversion
// ---------------------------------------------------------------------------
__global__ void cvt_bf16_k(const float* __restrict__ in, short* __restrict__ out, int n) {
    int i = blockIdx.x * blockDim.x + threadIdx.x;
    if (i < n) out[i] = f2bf(in[i]);
}

__global__ void cvt_bf16_t_k(const float* __restrict__ in, short* __restrict__ out, int K, int N) {
    int i = blockIdx.x * blockDim.x + threadIdx.x;
    if (i >= K * N) return;
    int nn = i >> HBITS;
    int kk = i & (NODES_H - 1);
    out[i] = f2bf(in[kk * N + nn]);  // out[n][k] = in[k][n], K==128
}

// ---------------------------------------------------------------------------
// CSR build: node histogram -> scan -> bucketed two-stage reorder
// ---------------------------------------------------------------------------
__global__ void zero_cnt_k(int* __restrict__ cnt, int N) {
    int i = blockIdx.x * blockDim.x + threadIdx.x;
    if (i < N) cnt[i] = 0;
}

__global__ void count_k(const int* __restrict__ dst, int* __restrict__ cnt, int E) {
    int e = blockIdx.x * blockDim.x + threadIdx.x;
    if (e < E) atomicAdd(&cnt[dst[e]], 1);
}

__global__ __launch_bounds__(256) void scan1_k(const int* __restrict__ cnt,
                                               int* __restrict__ rowptr,
                                               int* __restrict__ bsum, int N) {
    __shared__ int buf[256];
    int tid = threadIdx.x;
    int i = blockIdx.x * 256 + tid;
    int v = (i < N) ? cnt[i] : 0;
    buf[tid] = v;
    __syncthreads();
#pragma unroll
    for (int off = 1; off < 256; off <<= 1) {
        int t = (tid >= off) ? buf[tid - off] : 0;
        __syncthreads();
        buf[tid] += t;
        __syncthreads();
    }
    if (i < N) rowptr[i] = buf[tid] - v;
    if (tid == 255) bsum[blockIdx.x] = buf[255];
}

__global__ __launch_bounds__(256) void scan2_k(int* __restrict__ bsum, int nb) {
    __shared__ int buf[256];
    int tid = threadIdx.x;
    int v = (tid < nb) ? bsum[tid] : 0;
    buf[tid] = v;
    __syncthreads();
#pragma unroll
    for (int off = 1; off < 256; off <<= 1) {
        int t = (tid >= off) ? buf[tid - off] : 0;
        __syncthreads();
        buf[tid] += t;
        __syncthreads();
    }
    if (tid < nb) bsum[tid] = buf[tid] - v;
}

// finalize node-level rowptr (+ dis)
__global__ void scan3_k(int* __restrict__ rowptr, const int* __restrict__ bsum,
                        const int* __restrict__ cnt, float* __restrict__ dis,
                        int N, int E) {
    int i = blockIdx.x * blockDim.x + threadIdx.x;
    if (i < N) {
        rowptr[i] += bsum[blockIdx.x];
        dis[i] = rsqrtf((float)(cnt[i] + 1));
    }
    if (i == 0) rowptr[N] = E;
}

// generic scan finalize: data[i] += bsum[i/256]
__global__ void scanfin_k(int* __restrict__ data, const int* __restrict__ bsum, int n) {
    int i = blockIdx.x * blockDim.x + threadIdx.x;
    if (i < n) data[i] += bsum[i >> 8];
}

// Stage A: per-chunk bucket histogram. 256 chunks x 256 buckets (bucket = dst>>8).
__global__ __launch_bounds__(256) void binA_k(const int* __restrict__ dst,
                                              int* __restrict__ fcnt, int E, int CH) {
    __shared__ int lcnt[256];
    const int c = blockIdx.x, tid = threadIdx.x;
    lcnt[tid] = 0;
    __syncthreads();
    int base = c * CH, stop = min(E, base + CH);
    for (int e = base + tid; e < stop; e += 256)
        atomicAdd(&lcnt[dst[e] >> 8], 1);
    __syncthreads();
    fcnt[tid * 256 + c] = lcnt[tid];
}

// Stage B: scatter packed edges into bucket/chunk-ordered ubuf.
__global__ __launch_bounds__(256) void binB_k(const int* __restrict__ src,
                                              const int* __restrict__ dst,
                                              const int* __restrict__ foff,
                                              unsigned* __restrict__ ubuf, int E, int CH) {
    __shared__ int cur[256];
    const int c = blockIdx.x, tid = threadIdx.x;
    cur[tid] = foff[tid * 256 + c];
    __syncthreads();
    int base = c * CH, stop = min(E, base + CH);
    for (int e = base + tid; e < stop; e += 256) {
        int d = dst[e];
        int p = atomicAdd(&cur[d >> 8], 1);
        ubuf[p] = (((unsigned)(d & 255)) << 16) | (unsigned)src[e];
    }
}

// Stage C: per-bucket final CSR placement.
__global__ __launch_bounds__(256) void binC_k(const unsigned* __restrict__ ubuf,
                                              const int* __restrict__ foff,
                                              const int* __restrict__ rowptr,
                                              int* __restrict__ csr_src, int N, int E) {
    __shared__ int cur[256];
    const int b = blockIdx.x, tid = threadIdx.x;
    const int node0 = b << 8;
    if (node0 + tid < N) cur[tid] = rowptr[node0 + tid];
    __syncthreads();
    int beg = foff[b << 8];
    int end = (b < 255) ? foff[(b + 1) << 8] : E;
    for (int e = beg + tid; e < end; e += 256) {
        unsigned u = ubuf[e];
        int lnode = (int)(u >> 16);
        int p = atomicAdd(&cur[lnode], 1);
        csr_src[p] = (int)(u & 0xFFFFu);
    }
}

// ---------------------------------------------------------------------------
// h init (bf16 state only)
// ---------------------------------------------------------------------------
__global__ void h_init_k(const float* __restrict__ hc, unsigned short* __restrict__ hb,
                         int total) {
    int i = blockIdx.x * blockDim.x + threadIdx.x;
    if (i < total) hb[i] = (unsigned short)f2bf(hc[i & (NODES_H - 1)]);
}

// ---------------------------------------------------------------------------
// fp32 tiled GEMM (proj: K=16), bf16 output
// ---------------------------------------------------------------------------
#define BM 64
#define BN 64
#define BK 16

template <bool WT, bool RELU_A>
__global__ __launch_bounds__(256) void gemm_k(const float* __restrict__ A,
                                              const float* __restrict__ W,
                                              const float* __restrict__ bias,
                                              unsigned short* __restrict__ C,
                                              int M, int K, int N) {
    __shared__ float As[BK][BM + 1];
    __shared__ float Ws[BK][BN + 1];

    const int gn = N / BN;
    const int bx = blockIdx.x % gn;
    const int by = blockIdx.x / gn;
    const int tid = threadIdx.x;
    const int tx = tid & 15;
    const int ty = tid >> 4;
    const int row0 = by * BM;
    const int col0 = bx * BN;

    float acc[4][4] = {};

    for (int k0 = 0; k0 < K; k0 += BK) {
#pragma unroll
        for (int i = 0; i < 4; ++i) {
            int idx = tid + i * 256;
            int r = idx >> 4, k = idx & 15;
            int gr = row0 + r;
            float v = (gr < M) ? A[(size_t)gr * K + k0 + k] : 0.0f;
            if (RELU_A) v = fmaxf(v, 0.0f);
            As[k][r] = v;
        }
#pragma unroll
        for (int i = 0; i < 4; ++i) {
            int idx = tid + i * 256;
            if (!WT) {
                int k = idx >> 6, n = idx & 63;
                Ws[k][n] = W[(size_t)(k0 + k) * N + col0 + n];
            } else {
                int n = idx >> 4, k = idx & 15;
                Ws[k][n] = W[(size_t)(col0 + n) * K + k0 + k];
            }
        }
        __syncthreads();

#pragma unroll
        for (int kk = 0; kk < BK; ++kk) {
            float a[4], w[4];
#pragma unroll
            for (int i = 0; i < 4; ++i) a[i] = As[kk][ty * 4 + i];
#pragma unroll
            for (int j = 0; j < 4; ++j) w[j] = Ws[kk][tx * 4 + j];
#pragma unroll
            for (int i = 0; i < 4; ++i)
#pragma unroll
                for (int j = 0; j < 4; ++j) acc[i][j] += a[i] * w[j];
        }
        __syncthreads();
    }

#pragma unroll
    for (int i = 0; i < 4; ++i) {
        int gr = row0 + ty * 4 + i;
        if (gr >= M) continue;
#pragma unroll
        for (int j = 0; j < 4; ++j) {
            int gc = col0 + tx * 4 + j;
            float v = acc[i][j];
            if (bias) v += bias[gc];
            C[(size_t)gr * N + gc] = (unsigned short)f2bf(v);
        }
    }
}

// ---------------------------------------------------------------------------
// MFMA helpers, 64-row tile, wave split m4 x n2 (wave owns 32 cols, all rows).
// ---------------------------------------------------------------------------
struct BFrags { bf16x8 b[2][4]; };  // [n][ks]

static __device__ __forceinline__ void load_b(const short* __restrict__ Wg,
                                              int c0, int lrow, int lk, BFrags& f) {
#pragma unroll
    for (int n = 0; n < 2; ++n) {
        int cc = c0 + (n << 4) + lrow;
#pragma unroll
        for (int ks = 0; ks < 4; ++ks) {
            int chunk = (ks << 2) + lk;
            f.b[n][ks] = *(const bf16x8*)&Wg[((size_t)cc << 7) + (chunk << 3)];
        }
    }
}

static __device__ __forceinline__ void mfma_apply(const short* __restrict__ S,
                                                  const BFrags& f, int lrow, int lk,
                                                  f32x4 acc[4][2]) {
#pragma unroll
    for (int ks = 0; ks < 4; ++ks) {
        int chunk = (ks << 2) + lk;
        bf16x8 a[4];
#pragma unroll
        for (int m = 0; m < 4; ++m) {
            int rr = (m << 4) + lrow;
            a[m] = *(const bf16x8*)&S[rr * 128 + ((chunk ^ (rr & 7)) << 3)];
        }
#pragma unroll
        for (int m = 0; m < 4; ++m)
#pragma unroll
            for (int n = 0; n < 2; ++n)
                acc[m][n] = __builtin_amdgcn_mfma_f32_16x16x32_bf16(a[m], f.b[n][ks], acc[m][n], 0, 0, 0);
    }
}

// swizzled LDS element access
static __device__ __forceinline__ float lds_bf16(const short* __restrict__ S, int r, int c) {
    return bf2f((unsigned short)S[r * 128 + (((c >> 3) ^ (r & 7)) << 3) + (c & 7)]);
}
static __device__ __forceinline__ void lds_put_bf16(short* __restrict__ S, int r, int c, short v) {
    S[r * 128 + (((c >> 3) ^ (r & 7)) << 3) + (c & 7)] = v;
}

// ---------------------------------------------------------------------------
// bf16 MFMA GEMM (conv2): C = relu?(A) @ Wt^T, bf16 out. K=N=128, 64-row tile.
// ---------------------------------------------------------------------------
template <bool RELU_A>
__global__ __launch_bounds__(256, 4) void gemm_mfma_k(const unsigned short* __restrict__ A,
                                                      const short* __restrict__ Wt,
                                                      unsigned short* __restrict__ C,
                                                      int M) {
    __shared__ short As[64 * 128];

    const int row0 = blockIdx.x << 6;
    const int tid = threadIdx.x;

#pragma unroll
    for (int i = 0; i < 4; ++i) {
        int chunk = tid + (i << 8);
        int r = chunk >> 4, c = chunk & 15;
        int gr = row0 + r;
        bf16x8 t;
        if (gr < M) {
            t = *(const bf16x8*)(A + (((size_t)gr) << 7) + (c << 3));
            if (RELU_A) {
#pragma unroll
                for (int j = 0; j < 8; ++j) {
                    unsigned short u = (unsigned short)t[j];
                    t[j] = (short)((u & 0x8000u) ? 0 : u);
                }
            }
        } else {
#pragma unroll
            for (int j = 0; j < 8; ++j) t[j] = 0;
        }
        *(bf16x8*)&As[r * 128 + ((c ^ (r & 7)) << 3)] = t;
    }

    const int lane = tid & 63;
    const int wid = tid >> 6;
    const int c0 = wid << 5;
    const int lrow = lane & 15;
    const int lk = lane >> 4;

    BFrags bf;
    load_b(Wt, c0, lrow, lk, bf);  // overlap with staging
    __syncthreads();

    f32x4 acc[4][2] = {};
    mfma_apply(As, bf, lrow, lk, acc);

#pragma unroll
    for (int m = 0; m < 4; ++m) {
#pragma unroll
        for (int j = 0; j < 4; ++j) {
            int gr = row0 + (m << 4) + (lk << 2) + j;
            if (gr >= M) continue;
#pragma unroll
            for (int n = 0; n < 2; ++n) {
                int gc = c0 + (n << 4) + lrow;
                C[((size_t)gr << 7) + gc] = (unsigned short)f2bf(acc[m][n][j]);
            }
        }
    }
}

// ---------------------------------------------------------------------------
// Fused GRU (64-row tile, m4 x n2): six gate GEMM passes, B double-buffered,
// (256,2) no-spill, fast gate math. FUSE_CONV: after h' epilogue, restage h'
// in LDS and run conv1 (h'@cWt^T) in the same kernel -> writes HWout.
// ---------------------------------------------------------------------------
template <bool RELU_A, bool FUSE_CONV>
__global__ __launch_bounds__(256, 2) void gru_fused_k(const unsigned short* __restrict__ A,
                                                      const unsigned short* __restrict__ hb,
                                                      const short* __restrict__ WihT,
                                                      const short* __restrict__ WhhT,
                                                      const float* __restrict__ bih,
                                                      const float* __restrict__ bhh,
                                                      const short* __restrict__ cWt,
                                                      unsigned short* __restrict__ hnb,
                                                      unsigned short* __restrict__ HWout,
                                                      int M) {
    __shared__ short As[64 * 128];
    __shared__ short Hs[64 * 128];

    const int row0 = blockIdx.x << 6;
    const int tid = threadIdx.x;

    // stage A (relu optional) and h tiles
#pragma unroll
    for (int i = 0; i < 4; ++i) {
        int chunk = tid + (i << 8);
        int r = chunk >> 4, c = chunk & 15;
        int gr = row0 + r;
        bf16x8 ta, th;
        if (gr < M) {
            ta = *(const bf16x8*)(A + (((size_t)gr) << 7) + (c << 3));
            if (RELU_A) {
#pragma unroll
                for (int j = 0; j < 8; ++j) {
                    unsigned short u = (unsigned short)ta[j];
                    ta[j] = (short)((u & 0x8000u) ? 0 : u);
                }
            }
            th = *(const bf16x8*)(hb + (((size_t)gr) << 7) + (c << 3));
        } else {
#pragma unroll
            for (int j = 0; j < 8; ++j) { ta[j] = 0; th[j] = 0; }
        }
        int sw = r * 128 + ((c ^ (r & 7)) << 3);
        *(bf16x8*)&As[sw] = ta;
        *(bf16x8*)&Hs[sw] = th;
    }

    const int lane = tid & 63;
    const int wid = tid >> 6;
    const int c0 = wid << 5;
    const int lrow = lane & 15;
    const int lk = lane >> 4;

    // biases for this lane's columns
    float br[2], bz[2], bni[2], bnh[2];
#pragma unroll
    for (int n = 0; n < 2; ++n) {
        int gc = c0 + (n << 4) + lrow;
        br[n] = bih[gc] + bhh[gc];
        bz[n] = bih[128 + gc] + bhh[128 + gc];
        bni[n] = bih[256 + gc];
        bnh[n] = bhh[256 + gc];
    }

    const int GS = 128 * 128;  // per-gate weight stride
    BFrags bfA, bfB;
    load_b(WihT, c0, lrow, lk, bfA);           // pass 1 B (overlaps staging)
    load_b(WhhT, c0, lrow, lk, bfB);           // pass 2 B (overlaps staging)
    __syncthreads();

    f32x4 accR[4][2] = {};
    f32x4 accT[4][2] = {};

    mfma_apply(As, bfA, lrow, lk, accR);       // gi_r
    load_b(WhhT + 2 * GS, c0, lrow, lk, bfA);  // prefetch pass 3 (gh_n)
    mfma_apply(Hs, bfB, lrow, lk, accR);       // + gh_r
    load_b(WihT + 2 * GS, c0, lrow, lk, bfB);  // prefetch pass 4 (gi_n)
    mfma_apply(Hs, bfA, lrow, lk, accT);       // gh_n
    load_b(WihT + GS, c0, lrow, lk, bfA);      // prefetch pass 5 (gi_z)

    // fold: accT = r * (gh_n + bnh)   [accR dead after this]
#pragma unroll
    for (int m = 0; m < 4; ++m)
#pragma unroll
        for (int n = 0; n < 2; ++n)
#pragma unroll
            for (int j = 0; j < 4; ++j) {
                float rr = fast_sigmoid(accR[m][n][j] + br[n]);
                accT[m][n][j] = rr * (accT[m][n][j] + bnh[n]);
            }

    mfma_apply(As, bfB, lrow, lk, accT);       // += gi_n
    load_b(WhhT + GS, c0, lrow, lk, bfB);      // prefetch pass 6 (gh_z)

    // n = tanh(accT + bni)
#pragma unroll
    for (int m = 0; m < 4; ++m)
#pragma unroll
        for (int n = 0; n < 2; ++n)
#pragma unroll
            for (int j = 0; j < 4; ++j)
                accT[m][n][j] = fast_tanh(accT[m][n][j] + bni[n]);

    f32x4 accZ[4][2] = {};
    mfma_apply(As, bfA, lrow, lk, accZ);       // gi_z
    mfma_apply(Hs, bfB, lrow, lk, accZ);       // + gh_z

    if (FUSE_CONV) {
        load_b(cWt, c0, lrow, lk, bfA);        // prefetch conv1 B
        __syncthreads();                       // all waves done reading As
    }

    // epilogue: z, h' = (1-z)*n + z*h ; store global (+ LDS As if fusing)
#pragma unroll
    for (int m = 0; m < 4; ++m) {
#pragma unroll
        for (int j = 0; j < 4; ++j) {
            int lr = (m << 4) + (lk << 2) + j;
            int grow = row0 + lr;
            if (grow >= M) continue;
#pragma unroll
            for (int n = 0; n < 2; ++n) {
                int gcol = c0 + (n << 4) + lrow;
                float zz = fast_sigmoid(accZ[m][n][j] + bz[n]);
                float hv = lds_bf16(Hs, lr, gcol);
                float v = (1.0f - zz) * accT[m][n][j] + zz * hv;
                short vb = f2bf(v);
                hnb[((size_t)grow << 7) + gcol] = (unsigned short)vb;
                if (FUSE_CONV) lds_put_bf16(As, lr, gcol, vb);
            }
        }
    }

    if (FUSE_CONV) {
        __syncthreads();                       // h' tile complete in As
        f32x4 accC[4][2] = {};
        mfma_apply(As, bfA, lrow, lk, accC);   // HW = h' @ cWt^T
#pragma unroll
        for (int m = 0; m < 4; ++m) {
#pragma unroll
            for (int j = 0; j < 4; ++j) {
                int gr = row0 + (m << 4) + (lk << 2) + j;
                if (gr >= M) continue;
#pragma unroll
                for (int n = 0; n < 2; ++n) {
                    int gc = c0 + (n << 4) + lrow;
                    HWout[((size_t)gr << 7) + gc] = (unsigned short)f2bf(accC[m][n][j]);
                }
            }
        }
    }
}

// ---------------------------------------------------------------------------
// GCN gather (pull): one wave per destination node, bf16 HW rows, 4-edge unroll
// ---------------------------------------------------------------------------
__global__ __launch_bounds__(256) void gcn_gather_k(const unsigned short* __restrict__ HW,
                                                    const float* __restrict__ dis,
                                                    const int* __restrict__ rowptr,
                                                    const int* __restrict__ csr_src,
                                                    const float* __restrict__ bias,
                                                    unsigned short* __restrict__ out, int N) {
    int node = (blockIdx.x * 256 + threadIdx.x) >> 6;
    int lane = threadIdx.x & 63;
    if (node >= N) return;
    float dd = dis[node];
    unsigned v0 = *(const unsigned*)&HW[((size_t)node << HBITS) + (lane << 1)];
    float2 b2 = *(const float2*)&bias[lane << 1];
    float accx = bf2f((unsigned short)(v0 & 0xFFFFu)) * dd;
    float accy = bf2f((unsigned short)(v0 >> 16)) * dd;
    int e = rowptr[node], end = rowptr[node + 1];
    for (; e + 3 < end; e += 4) {
        int s0 = csr_src[e], s1 = csr_src[e + 1], s2 = csr_src[e + 2], s3 = csr_src[e + 3];
        float w0 = dis[s0], w1 = dis[s1], w2 = dis[s2], w3 = dis[s3];
        unsigned a = *(const unsigned*)&HW[((size_t)s0 << HBITS) + (lane << 1)];
        unsigned b = *(const unsigned*)&HW[((size_t)s1 << HBITS) + (lane << 1)];
        unsigned c = *(const unsigned*)&HW[((size_t)s2 << HBITS) + (lane << 1)];
        unsigned d = *(const unsigned*)&HW[((size_t)s3 << HBITS) + (lane << 1)];
        accx += bf2f((unsigned short)(a & 0xFFFFu)) * w0;
        accy += bf2f((unsigned short)(a >> 16)) * w0;
        accx += bf2f((unsigned short)(b & 0xFFFFu)) * w1;
        accy += bf2f((unsigned short)(b >> 16)) * w1;
        accx += bf2f((unsigned short)(c & 0xFFFFu)) * w2;
        accy += bf2f((unsigned short)(c >> 16)) * w2;
        accx += bf2f((unsigned short)(d & 0xFFFFu)) * w3;
        accy += bf2f((unsigned short)(d >> 16)) * w3;
    }
    for (; e < end; ++e) {
        int s = csr_src[e];
        float w = dis[s];
        unsigned a = *(const unsigned*)&HW[((size_t)s << HBITS) + (lane << 1)];
        accx += bf2f((unsigned short)(a & 0xFFFFu)) * w;
        accy += bf2f((unsigned short)(a >> 16)) * w;
    }
    accx = accx * dd + b2.x;
    accy = accy * dd + b2.y;
    unsigned o = ((unsigned)(unsigned short)f2bf(accy) << 16) | (unsigned short)f2bf(accx);
    *(unsigned*)&out[((size_t)node << HBITS) + (lane << 1)] = o;
}

// ---------------------------------------------------------------------------
// Output head (bf16 h input)
// ---------------------------------------------------------------------------
#define OUT_DIM 5
__global__ void out_softmax_k(const unsigned short* __restrict__ h,
                              const float* __restrict__ Wo,
                              const float* __restrict__ bo, float* __restrict__ out, int N) {
    int gtid = blockIdx.x * blockDim.x + threadIdx.x;
    int node = gtid >> 6;
    int lane = threadIdx.x & 63;
    if (node >= N) return;
    const unsigned short* hr = h + ((size_t)node << HBITS);
    float h0 = bf2f(hr[lane]);
    float h1 = bf2f(hr[lane + 64]);
    float acc[OUT_DIM];
#pragma unroll
    for (int o = 0; o < OUT_DIM; ++o)
        acc[o] = h0 * Wo[lane * OUT_DIM + o] + h1 * Wo[(lane + 64) * OUT_DIM + o];
#pragma unroll
    for (int off = 32; off >= 1; off >>= 1) {
#pragma unroll
        for (int o = 0; o < OUT_DIM; ++o) acc[o] += __shfl_down(acc[o], off, 64);
    }
    if (lane == 0) {
        float v[OUT_DIM], m = -1e30f;
#pragma unroll
        for (int o = 0; o < OUT_DIM; ++o) { v[o] = acc[o] + bo[o]; m = fmaxf(m, v[o]); }
        float s = 0.0f;
#pragma unroll
        for (int o = 0; o < OUT_DIM; ++o) { v[o] = __builtin_amdgcn_exp2f((v[o] - m) * LOG2E); s += v[o]; }
        float inv = 1.0f / s;
#pragma unroll
        for (int o = 0; o < OUT_DIM; ++o) out[(size_t)node * OUT_DIM + o] = v[o] * inv;
    }
}

// ---------------------------------------------------------------------------
// launch
// ---------------------------------------------------------------------------
static inline int cdiv(long long a, long long b) { return (int)((a + b - 1) / b); }
static inline char* align256(char* p) {
    return (char*)(((uintptr_t)p + 255) & ~(uintptr_t)255);
}

extern "C" void kernel_launch(void* const* d_in, const int* in_sizes, int n_in,
                              void* d_out, int out_size, void* d_ws, size_t ws_size,
                              hipStream_t stream) {
    const float* x       = (const float*)d_in[0];
    const int*   eidx    = (const int*)d_in[1];
    const float* proj_W  = (const float*)d_in[2];
    const float* proj_b  = (const float*)d_in[3];
    const float* conv1_W = (const float*)d_in[4];
    const float* conv1_b = (const float*)d_in[5];
    const float* conv2_W = (const float*)d_in[6];
    const float* conv2_b = (const float*)d_in[7];
    const float* hidden_c= (const float*)d_in[8];
    const float* gru_Wih = (const float*)d_in[9];
    const float* gru_Whh = (const float*)d_in[10];
    const float* gru_bih = (const float*)d_in[11];
    const float* gru_bhh = (const float*)d_in[12];
    const float* out_W   = (const float*)d_in[13];
    const float* out_b   = (const float*)d_in[14];
    float* out = (float*)d_out;

    const int F = 16, H = 128, G3 = 384;
    const int N = in_sizes[0] / F;
    const int E = in_sizes[1] / 2;
    const int* src = eidx;
    const int* dst = eidx + E;

    const int TPB = 256;
    const int nScanBlocks = cdiv(N, 256);
    const int CH = cdiv(E, 256);
    const int FLAT = 256 * 256;

    // workspace (256B-aligned slots)
    char* wp = (char*)d_ws;
#define ALLOC(ptr_t, name, bytes) ptr_t name = (ptr_t)wp; wp = align256(wp + (bytes))
    ALLOC(int*, cnt, (size_t)N * 4);
    ALLOC(int*, rowptr, (size_t)(N + 1) * 4);
    ALLOC(int*, bsum, 256 * 4);
    ALLOC(int*, fcnt, (size_t)FLAT * 4);
    ALLOC(int*, foff, (size_t)FLAT * 4);
    ALLOC(int*, bsum2, 256 * 4);
    ALLOC(unsigned*, ubuf, (size_t)E * 4);
    ALLOC(int*, csr_src, (size_t)E * 4);
    ALLOC(float*, dis, (size_t)N * 4);
    ALLOC(short*, c1Wt, (size_t)H * H * 2);
    ALLOC(short*, c2Wt, (size_t)H * H * 2);
    ALLOC(short*, WihT, (size_t)G3 * H * 2);
    ALLOC(short*, WhhT, (size_t)G3 * H * 2);
    ALLOC(unsigned short*, h0b, (size_t)N * H * 2);
    ALLOC(unsigned short*, h1b, (size_t)N * H * 2);
    ALLOC(unsigned short*, Abuf, (size_t)N * H * 2);
    ALLOC(unsigned short*, HWb, (size_t)N * H * 2);
#undef ALLOC

    const int totNH = N * H;

    // --- weight preconversion (bf16, [n][k]) ---
    cvt_bf16_t_k<<<cdiv(H * H, TPB), TPB, 0, stream>>>(conv1_W, c1Wt, H, H);
    cvt_bf16_t_k<<<cdiv(H * H, TPB), TPB, 0, stream>>>(conv2_W, c2Wt, H, H);
    cvt_bf16_k<<<cdiv(G3 * H, TPB), TPB, 0, stream>>>(gru_Wih, WihT, G3 * H);
    cvt_bf16_k<<<cdiv(G3 * H, TPB), TPB, 0, stream>>>(gru_Whh, WhhT, G3 * H);

    // --- node histogram + rowptr + dis ---
    zero_cnt_k<<<cdiv(N, TPB), TPB, 0, stream>>>(cnt, N);
    count_k<<<cdiv(E, TPB), TPB, 0, stream>>>(dst, cnt, E);
    scan1_k<<<nScanBlocks, 256, 0, stream>>>(cnt, rowptr, bsum, N);
    scan2_k<<<1, 256, 0, stream>>>(bsum, nScanBlocks);
    scan3_k<<<nScanBlocks, 256, 0, stream>>>(rowptr, bsum, cnt, dis, N, E);

    // --- bucketed reorder ---
    binA_k<<<256, 256, 0, stream>>>(dst, fcnt, E, CH);
    scan1_k<<<256, 256, 0, stream>>>(fcnt, foff, bsum2, FLAT);
    scan2_k<<<1, 256, 0, stream>>>(bsum2, 256);
    scanfin_k<<<cdiv(FLAT, TPB), TPB, 0, stream>>>(foff, bsum2, FLAT);
    binB_k<<<256, 256, 0, stream>>>(src, dst, foff, ubuf, E, CH);
    binC_k<<<cdiv(N, 256), 256, 0, stream>>>(ubuf, foff, rowptr, csr_src, N, E);

    // --- h init (bf16) ---
    h_init_k<<<cdiv(totNH, TPB), TPB, 0, stream>>>(hidden_c, h0b, totNH);

    unsigned short* hb_cur = h0b;
    unsigned short* hb_nxt = h1b;

    const int gm64 = cdiv(N, 64);
    const int gatherBlocks = cdiv((long long)N * 64, TPB);

    // --- proj (K=16, fp32 path, bf16 out) ---
    dim3 gridP(cdiv(N, BM) * (H / BN));
    gemm_k<false, false><<<gridP, TPB, 0, stream>>>(x, proj_W, proj_b, Abuf, N, F, H);

    // --- GRU step 0 (fused, + conv1 of it=0) ---
    gru_fused_k<false, true><<<gm64, TPB, 0, stream>>>(Abuf, hb_cur, WihT, WhhT,
                                                       gru_bih, gru_bhh, c1Wt,
                                                       hb_nxt, HWb, N);
    { unsigned short* t = hb_cur; hb_cur = hb_nxt; hb_nxt = t; }

    for (int it = 0; it < 3; ++it) {
        // HWb already holds hb_cur @ conv1_W (from fused GRU)
        gcn_gather_k<<<gatherBlocks, TPB, 0, stream>>>(HWb, dis, rowptr, csr_src,
                                                       conv1_b, Abuf, N);
        gemm_mfma_k<true><<<gm64, TPB, 0, stream>>>(Abuf, c2Wt, HWb, N);
        gcn_gather_k<<<gatherBlocks, TPB, 0, stream>>>(HWb, dis, rowptr, csr_src,
                                                       conv2_b, Abuf, N);
        if (it < 2) {
            gru_fused_k<true, true><<<gm64, TPB, 0, stream>>>(Abuf, hb_cur, WihT, WhhT,
                                                              gru_bih, gru_bhh, c1Wt,
                                                              hb_nxt, HWb, N);
        } else {
            gru_fused_k<true, false><<<gm64, TPB, 0, stream>>>(Abuf, hb_cur, WihT, WhhT,
                                                               gru_bih, gru_bhh, nullptr,
                                                               hb_nxt, nullptr, N);
        }
        { unsigned short* t = hb_cur; hb_cur = hb_nxt; hb_nxt = t; }
    }

    // --- output head ---
    out_softmax_k<<<cdiv((long long)N * 64, TPB), TPB, 0, stream>>>(hb_cur, out_W, out_b, out, N);
}